// Round 16
// baseline (544.847 us; speedup 1.0000x reference)
//
#include <hip/hip_runtime.h>
#include <cmath>

#define B_N 2
#define NFR 8
#define HH 32
#define WW 32
#define LSEQ 8192
#define DIMD 384
#define DI 192
#define DST 16
#define DRK 24
#define HID 1536
#define MR (B_N*LSEQ)   // 16384 rows

#define NCH 256         // scan chunks
#define CL  (LSEQ/NCH)  // 32 steps per chunk
#define PSL 128         // pool slices

typedef __attribute__((ext_vector_type(8))) short  bf16x8;
typedef __attribute__((ext_vector_type(4))) float  f32x4;
typedef __attribute__((ext_vector_type(8))) unsigned short u16x8;

// ---------------- workspace layout (floats) ----------------
constexpr size_t SZ_BLD = (size_t)MR * DIMD;   // 6291456
constexpr size_t SZ_BLI = (size_t)MR * DI;     // 3145728
constexpr size_t SZ_DBL = (size_t)MR * 56;     // 917504

constexpr size_t OFF_XFLAT = 0;
constexpr size_t OFF_FFLAT = OFF_XFLAT + SZ_BLD;
constexpr size_t OFF_XZ    = OFF_FFLAT + SZ_BLD;
constexpr size_t OFF_XCF   = OFF_XZ + SZ_BLD;
constexpr size_t OFF_XCR   = OFF_XCF + SZ_BLI;
constexpr size_t OFF_H1    = 0;
constexpr size_t OFF_PK    = 0;                     // fc2 split-K partials (3x SZ_BLD)
constexpr size_t OFF_R2    = OFF_XCR + SZ_BLI;      // 25165824
constexpr size_t OFF_DBLF  = OFF_R2;
constexpr size_t OFF_DBLR  = OFF_DBLF + SZ_DBL;
constexpr size_t OFF_DTF   = OFF_DBLR + SZ_DBL;
constexpr size_t OFF_DTR   = OFF_DTF + SZ_BLI;
constexpr size_t OFF_GF    = OFF_DTR + SZ_BLI;      // bf16 g_f
constexpr size_t OFF_GR    = OFF_GF + SZ_BLI;       // bf16 g_r
constexpr size_t OFF_MF    = OFF_GR + SZ_BLI;
constexpr size_t OFF_MR_   = OFF_MF + SZ_BLD;
constexpr size_t OFF_H2    = OFF_R2;                // bf16 h2
constexpr size_t OFF_NORM  = OFF_MR_ + SZ_BLD;      // bf16 normed1/2; later f32 outm
constexpr size_t OFF_XM    = OFF_NORM + SZ_BLD;
constexpr size_t OFF_PART  = OFF_XM + SZ_BLD;       // pool partials; later dwwT
constexpr size_t OFF_AW    = OFF_PART + (size_t)6*PSL*384;
constexpr size_t OFF_INV   = OFF_AW + 2*3*384;      // 8192 ints
constexpr size_t OFF_WBF   = OFF_INV + 8192;        // bf16 weight copies (shorts)
constexpr size_t WB_INP = 0;                         // 384x384   = 147456
constexpr size_t WB_OUT = WB_INP + 147456;           // 384x192   = 73728
constexpr size_t WB_FC1 = WB_OUT + 73728;            // 1536x384  = 589824
constexpr size_t WB_FC2 = WB_FC1 + 589824;           // 384x1536  = 589824
constexpr size_t WB_TOT = WB_FC2 + 589824;
// scan chunk summaries alias dead normed+xm regions:
constexpr size_t SZ_CH   = (size_t)2*B_N*NCH*DI*16;  // 3145728
constexpr size_t OFF_CA  = OFF_NORM;
constexpr size_t OFF_CB  = OFF_CA + SZ_CH;
constexpr size_t OFF_CHS = OFF_CB + SZ_CH;
static_assert(OFF_CHS + SZ_CH <= OFF_PART, "scan summaries overflow");
static_assert(27*HID <= 6*PSL*384, "dwwT overflows part region");

__device__ __forceinline__ float siluf(float x){ return x / (1.f + expf(-x)); }
__device__ __forceinline__ float softplusf(float x){ return x > 20.f ? x : log1pf(expf(x)); }
// tanh-approx GELU (max abs err ~3e-4, below bf16 rounding of the consumer)
__device__ __forceinline__ float gelut(float x){
    float z = 0.7978845608f*(x + 0.044715f*x*x*x);
    float e = __expf(2.f*z);
    float t = 1.f - 2.f/(e + 1.f);
    return 0.5f*x*(1.f + t);
}
__device__ __forceinline__ unsigned short f2bf(float f){
    union { float f; unsigned int u; } v; v.f = f;
    unsigned int u = v.u + 0x7fffu + ((v.u >> 16) & 1u);
    return (unsigned short)(u >> 16);
}

#if __has_builtin(__builtin_amdgcn_global_load_lds)
#define HAVE_GLL 1
__device__ __forceinline__ void gload16(const void* g, void* l){
    __builtin_amdgcn_global_load_lds((const __attribute__((address_space(1))) void*)g,
                                     (__attribute__((address_space(3))) void*)l, 16, 0, 0);
}
#else
#define HAVE_GLL 0
#endif

// ============ inverse permutation ============
__global__ __launch_bounds__(256)
void k_inv(const int* __restrict__ hc, int* __restrict__ inv)
{
    int l = blockIdx.x*256 + threadIdx.x;
    inv[hc[l]] = l;
}

// ============ weight f32->bf16 conversion ============
__global__ __launch_bounds__(256)
void k_wcvt(const float* __restrict__ inpw, const float* __restrict__ outpw,
            const float* __restrict__ fc1w, const float* __restrict__ fc2w,
            unsigned short* __restrict__ wbf)
{
    int idx = blockIdx.x*256 + threadIdx.x;
    if (idx < 147456)                wbf[WB_INP + idx] = f2bf(inpw[idx]);
    else if (idx < 147456+73728)     wbf[WB_OUT + idx-147456] = f2bf(outpw[idx-147456]);
    else if (idx < 221184+589824)    wbf[WB_FC1 + idx-221184] = f2bf(fc1w[idx-221184]);
    else if (idx < 811008+589824)    wbf[WB_FC2 + idx-811008] = f2bf(fc2w[idx-811008]);
}

// ============ dw weight transpose ============
__global__ __launch_bounds__(256)
void k_wt(const float* __restrict__ dww, float* __restrict__ dwwT)
{
    int idx = blockIdx.x*256 + threadIdx.x;
    if (idx < 27*HID){
        int c = idx / 27, i = idx % 27;
        dwwT[i*HID + c] = dww[idx];
    }
}

// ============ gather (transpose-tile) + LayerNorm1, phase-split ============
__global__ __launch_bounds__(256)
void k_gather_ln(const float* __restrict__ x, const float* __restrict__ fx,
                 const int* __restrict__ inv, const float* __restrict__ lw,
                 const float* __restrict__ lb, float* __restrict__ x_flat,
                 float* __restrict__ f_flat, unsigned short* __restrict__ normed)
{
    __shared__ float tile[DIMD*33];
    int hw0 = blockIdx.x * 32;
    int nf  = blockIdx.y;
    int zz  = blockIdx.z;
    int b = zz >> 1, ph = zz & 1;
    int t   = threadIdx.x;
    int hwi = t & 31, dr = t >> 5;
    int w = t >> 6, lane = t & 63;
    const float* src = (ph ? fx : x) + ((size_t)(b*NFR+nf)*DIMD)*1024 + hw0;

    for (int d0 = 0; d0 < DIMD; d0 += 8){
        int d = d0 + dr;
        tile[d*33 + hwi] = src[(size_t)d*1024 + hwi];
    }
    __syncthreads();
    if (ph == 0){
        #pragma unroll
        for (int i = 0; i < 8; ++i){
            int r = w*8 + i;
            int l = inv[nf*1024 + hw0 + r];
            size_t rowo = (size_t)(b*LSEQ + l)*DIMD;
            float v[6]; float s = 0.f, s2 = 0.f;
            #pragma unroll
            for (int c = 0; c < 6; ++c){
                float a = tile[(c*64 + lane)*33 + r];
                v[c] = a; s += a; s2 += a*a;
            }
            #pragma unroll
            for (int o = 1; o < 64; o <<= 1){ s += __shfl_xor(s, o); s2 += __shfl_xor(s2, o); }
            float mean = s * (1.f/DIMD);
            float var  = s2 * (1.f/DIMD) - mean*mean;
            float rs = rsqrtf(var + 1e-5f);
            #pragma unroll
            for (int c = 0; c < 6; ++c){
                int d = c*64 + lane;
                x_flat[rowo + d] = v[c];
                normed[rowo + d] = f2bf((v[c]-mean)*rs*lw[d] + lb[d]);
            }
        }
    } else {
        #pragma unroll
        for (int i = 0; i < 8; ++i){
            int r = w*8 + i;
            int l = inv[nf*1024 + hw0 + r];
            size_t rowo = (size_t)(b*LSEQ + l)*DIMD;
            #pragma unroll
            for (int c = 0; c < 6; ++c)
                f_flat[rowo + c*64 + lane] = tile[(c*64 + lane)*33 + r];
        }
    }
}

// ============ output scatter, sums outm + 3 split-K partials ============
__global__ __launch_bounds__(256)
void k_scatter(const float* __restrict__ outm, const float* __restrict__ pk,
               const int* __restrict__ inv, float* __restrict__ outp)
{
    __shared__ float tile[DIMD*33];
    int hw0 = blockIdx.x * 32;
    int nf  = blockIdx.y;
    int b   = blockIdx.z;
    int t   = threadIdx.x;
    int hwi = t & 31, dr = t >> 5;
    int w = t >> 6, lane = t & 63;
    #pragma unroll
    for (int i = 0; i < 8; ++i){
        int r = w*8 + i;
        int l = inv[nf*1024 + hw0 + r];
        size_t rowo = (size_t)(b*LSEQ + l)*DIMD;
        #pragma unroll
        for (int c = 0; c < 6; ++c){
            size_t o = rowo + c*64 + lane;
            tile[(c*64 + lane)*33 + r] = outm[o] + pk[o] + pk[SZ_BLD + o] + pk[2*SZ_BLD + o];
        }
    }
    __syncthreads();
    float* ob = outp + ((size_t)(b*NFR+nf)*DIMD)*1024 + hw0;
    for (int d0 = 0; d0 < DIMD; d0 += 8){
        int d = d0 + dr;
        ob[(size_t)d*1024 + hwi] = tile[d*33 + hwi];
    }
}

// ============ fused xm + LayerNorm2: xm = x+Σaw*seq; nrm = LN(xm) ============
__global__ __launch_bounds__(128)
void k_xm_ln(const float* __restrict__ x_flat, const float* __restrict__ m_f,
             const float* __restrict__ m_r, const float* __restrict__ f_flat,
             const float* __restrict__ aw, const float* __restrict__ lw,
             const float* __restrict__ lb, float* __restrict__ xm,
             unsigned short* __restrict__ out)
{
    size_t row = blockIdx.x;
    int b = (int)(row >> 13);
    int t = threadIdx.x;
    float v[3]; float s = 0.f, s2 = 0.f;
    #pragma unroll
    for (int i = 0; i < 3; ++i){
        int d = t + i*128;
        size_t o = row*DIMD + d;
        float a0 = aw[(size_t)(b*3+0)*DIMD + d];
        float a1 = aw[(size_t)(b*3+1)*DIMD + d];
        float a2 = aw[(size_t)(b*3+2)*DIMD + d];
        float val = x_flat[o] + a0*m_f[o] + a1*m_r[o] + a2*f_flat[o];
        xm[o] = val;
        v[i] = val; s += val; s2 += val*val;
    }
    #pragma unroll
    for (int o = 32; o > 0; o >>= 1){ s += __shfl_down(s, o); s2 += __shfl_down(s2, o); }
    __shared__ float sh[4];
    if ((t & 63) == 0){ sh[(t>>6)*2] = s; sh[(t>>6)*2+1] = s2; }
    __syncthreads();
    float S = sh[0] + sh[2], S2 = sh[1] + sh[3];
    float mean = S * (1.f/DIMD);
    float var  = S2 * (1.f/DIMD) - mean*mean;
    float r = rsqrtf(var + 1e-5f);
    #pragma unroll
    for (int i = 0; i < 3; ++i){
        int d = t + i*128;
        out[row*DIMD + d] = f2bf((v[i]-mean)*r*lw[d] + lb[d]);
    }
}

// ============ bf16 MFMA GEMM, both operands bf16, global_load_lds staging ============
template<int EPI>
__global__ __launch_bounds__(256, 2)
void k_bgemm(const unsigned short* __restrict__ A, const unsigned short* __restrict__ Wb,
             const float* __restrict__ bias, const float* __restrict__ add,
             float* __restrict__ C, int N, int Kext, int Kstr)
{
    __shared__ unsigned short As[128*32];
    __shared__ unsigned short Bs[128*32];
    int tid  = threadIdx.x;
    int wid  = tid >> 6, lane = tid & 63;
    int row0 = blockIdx.x * 128, col0 = blockIdx.y * 128;
    int wr = wid >> 1, wc = wid & 1;
    int lr = lane & 15, lg = lane >> 4;

    f32x4 acc[4][4];
    #pragma unroll
    for (int m = 0; m < 4; ++m)
        #pragma unroll
        for (int n = 0; n < 4; ++n) acc[m][n] = (f32x4){0.f,0.f,0.f,0.f};

    int s0 = wid*2048 + lane*16;
    int r0 = s0 >> 6, k0i = (s0 & 63) >> 1;
    int s1 = s0 + 1024;
    int r1 = s1 >> 6, k1i = (s1 & 63) >> 1;
    const unsigned short* Ag0 = A  + (size_t)(row0 + r0)*Kstr + k0i;
    const unsigned short* Ag1 = A  + (size_t)(row0 + r1)*Kstr + k1i;
    const unsigned short* Bg0 = Wb + (size_t)(col0 + r0)*Kstr + k0i;
    const unsigned short* Bg1 = Wb + (size_t)(col0 + r1)*Kstr + k1i;

    const unsigned short* Ab = &As[(wr*64 + lr)*32 + lg*8];
    const unsigned short* Bb = &Bs[(wc*64 + lr)*32 + lg*8];

    for (int k0 = 0; k0 < Kext; k0 += 32){
        if (k0) __syncthreads();
#if HAVE_GLL
        gload16(Ag0, (char*)As + wid*2048);
        gload16(Ag1, (char*)As + wid*2048 + 1024);
        gload16(Bg0, (char*)Bs + wid*2048);
        gload16(Bg1, (char*)Bs + wid*2048 + 1024);
#else
        *(u16x8*)((char*)As + s0) = *(const u16x8*)Ag0;
        *(u16x8*)((char*)As + s1) = *(const u16x8*)Ag1;
        *(u16x8*)((char*)Bs + s0) = *(const u16x8*)Bg0;
        *(u16x8*)((char*)Bs + s1) = *(const u16x8*)Bg1;
#endif
        Ag0 += 32; Ag1 += 32; Bg0 += 32; Bg1 += 32;
        __syncthreads();
        bf16x8 af[4], bfr[4];
        #pragma unroll
        for (int m = 0; m < 4; ++m) af[m]  = *(const bf16x8*)(Ab + m*512);
        #pragma unroll
        for (int n = 0; n < 4; ++n) bfr[n] = *(const bf16x8*)(Bb + n*512);
        #pragma unroll
        for (int m = 0; m < 4; ++m)
            #pragma unroll
            for (int n = 0; n < 4; ++n)
                acc[m][n] = __builtin_amdgcn_mfma_f32_16x16x32_bf16(af[m], bfr[n], acc[m][n], 0, 0, 0);
    }

    #pragma unroll
    for (int m = 0; m < 4; ++m){
        #pragma unroll
        for (int r = 0; r < 4; ++r){
            int row = row0 + wr*64 + m*16 + lg*4 + r;
            #pragma unroll
            for (int n = 0; n < 4; ++n){
                int col = col0 + wc*64 + n*16 + lr;
                float v = acc[m][n][r];
                if (EPI >= 1) v += bias[col];
                if (EPI == 2) v += add[(size_t)row*N + col];
                C[(size_t)row*N + col] = v;
            }
        }
    }
}

// ============ fc2 split-K=4, bf16 both operands ============
__global__ __launch_bounds__(256, 2)
void k_bgemm_sk(const unsigned short* __restrict__ A, const unsigned short* __restrict__ Wb,
                const float* __restrict__ bias, const float* __restrict__ add,
                float* __restrict__ C0, float* __restrict__ PK, int N, int Kq, int Kstr)
{
    __shared__ unsigned short As[128*32];
    __shared__ unsigned short Bs[128*32];
    int tid  = threadIdx.x;
    int wid  = tid >> 6, lane = tid & 63;
    int row0 = blockIdx.x * 128, col0 = blockIdx.y * 128;
    int z = blockIdx.z;
    int kbeg = z * Kq;
    int wr = wid >> 1, wc = wid & 1;
    int lr = lane & 15, lg = lane >> 4;

    f32x4 acc[4][4];
    #pragma unroll
    for (int m = 0; m < 4; ++m)
        #pragma unroll
        for (int n = 0; n < 4; ++n) acc[m][n] = (f32x4){0.f,0.f,0.f,0.f};

    int s0 = wid*2048 + lane*16;
    int r0 = s0 >> 6, k0i = (s0 & 63) >> 1;
    int s1 = s0 + 1024;
    int r1 = s1 >> 6, k1i = (s1 & 63) >> 1;
    const unsigned short* Ag0 = A  + (size_t)(row0 + r0)*Kstr + kbeg + k0i;
    const unsigned short* Ag1 = A  + (size_t)(row0 + r1)*Kstr + kbeg + k1i;
    const unsigned short* Bg0 = Wb + (size_t)(col0 + r0)*Kstr + kbeg + k0i;
    const unsigned short* Bg1 = Wb + (size_t)(col0 + r1)*Kstr + kbeg + k1i;

    const unsigned short* Ab = &As[(wr*64 + lr)*32 + lg*8];
    const unsigned short* Bb = &Bs[(wc*64 + lr)*32 + lg*8];

    for (int k0 = 0; k0 < Kq; k0 += 32){
        if (k0) __syncthreads();
#if HAVE_GLL
        gload16(Ag0, (char*)As + wid*2048);
        gload16(Ag1, (char*)As + wid*2048 + 1024);
        gload16(Bg0, (char*)Bs + wid*2048);
        gload16(Bg1, (char*)Bs + wid*2048 + 1024);
#else
        *(u16x8*)((char*)As + s0) = *(const u16x8*)Ag0;
        *(u16x8*)((char*)As + s1) = *(const u16x8*)Ag1;
        *(u16x8*)((char*)Bs + s0) = *(const u16x8*)Bg0;
        *(u16x8*)((char*)Bs + s1) = *(const u16x8*)Bg1;
#endif
        Ag0 += 32; Ag1 += 32; Bg0 += 32; Bg1 += 32;
        __syncthreads();
        bf16x8 af[4], bfr[4];
        #pragma unroll
        for (int m = 0; m < 4; ++m) af[m]  = *(const bf16x8*)(Ab + m*512);
        #pragma unroll
        for (int n = 0; n < 4; ++n) bfr[n] = *(const bf16x8*)(Bb + n*512);
        #pragma unroll
        for (int m = 0; m < 4; ++m)
            #pragma unroll
            for (int n = 0; n < 4; ++n)
                acc[m][n] = __builtin_amdgcn_mfma_f32_16x16x32_bf16(af[m], bfr[n], acc[m][n], 0, 0, 0);
    }

    float* Cdst = (z == 0) ? C0 : (PK + (size_t)(z-1)*SZ_BLD);
    #pragma unroll
    for (int m = 0; m < 4; ++m){
        #pragma unroll
        for (int r = 0; r < 4; ++r){
            int row = row0 + wr*64 + m*16 + lg*4 + r;
            #pragma unroll
            for (int n = 0; n < 4; ++n){
                int col = col0 + wc*64 + n*16 + lr;
                float v = acc[m][n][r];
                if (z == 0) v += bias[col] + add[(size_t)row*N + col];
                Cdst[(size_t)row*N + col] = v;
            }
        }
    }
}

// ============ causal + anti-causal depthwise conv over L, + silu ============
__global__ __launch_bounds__(256)
void k_conv(const float* __restrict__ xz, const float* __restrict__ cw,
            const float* __restrict__ cb, float* __restrict__ xcf, float* __restrict__ xcr)
{
    const int TL = 64;
    int b = blockIdx.y;
    int l0 = blockIdx.x * TL;
    __shared__ float sx[TL+6][DI];
    for (int idx = threadIdx.x; idx < (TL+6)*DI; idx += 256){
        int r = idx / DI, c = idx % DI;
        int l = l0 + r - 3;
        float v = 0.f;
        if (l >= 0 && l < LSEQ) v = xz[((size_t)b*LSEQ + l)*DIMD + c];
        sx[r][c] = v;
    }
    __syncthreads();
    for (int idx = threadIdx.x; idx < TL*DI; idx += 256){
        int r = idx / DI, c = idx % DI;
        float w0 = cw[c*4+0], w1 = cw[c*4+1], w2 = cw[c*4+2], w3 = cw[c*4+3];
        float bi = cb[c];
        size_t orow = ((size_t)b*LSEQ + l0 + r)*DI + c;
        float af = bi + sx[r][c]*w0 + sx[r+1][c]*w1 + sx[r+2][c]*w2 + sx[r+3][c]*w3;
        xcf[orow] = siluf(af);
        float ar = bi + sx[r+3][c]*w3 + sx[r+4][c]*w2 + sx[r+5][c]*w1 + sx[r+6][c]*w0;
        xcr[orow] = siluf(ar);
    }
}

// ============ dbl = xc @ xproj_w^T  (N=56, K=192), both dirs ============
__global__ __launch_bounds__(256)
void k_dbl(const float* __restrict__ xc_f, const float* __restrict__ xc_r,
           const float* __restrict__ xpw,
           float* __restrict__ dbl_f, float* __restrict__ dbl_r)
{
    const float* xc  = blockIdx.y ? xc_r  : xc_f;
    float*       dbl = blockIdx.y ? dbl_r : dbl_f;
    __shared__ float sw[56*196];
    for (int i = threadIdx.x; i < 56*DI; i += 256){
        int n = i / DI, k = i % DI;
        sw[n*196 + k] = xpw[i];
    }
    __syncthreads();
    int lane = threadIdx.x & 63;
    int wid  = threadIdx.x >> 6;
    if (lane >= 56) return;
    const float* wrow = &sw[lane*196];
    #pragma unroll
    for (int g = 0; g < 2; ++g){
        int row0 = blockIdx.x*64 + g*32 + wid*8;
        const float* xr = xc + (size_t)row0*DI;
        float acc[8];
        #pragma unroll
        for (int r = 0; r < 8; ++r) acc[r] = 0.f;
        for (int k = 0; k < DI; k += 4){
            float4 w4 = *(const float4*)&wrow[k];
            #pragma unroll
            for (int r = 0; r < 8; ++r){
                float4 x4 = *(const float4*)&xr[(size_t)r*DI + k];
                acc[r] += x4.x*w4.x + x4.y*w4.y + x4.z*w4.z + x4.w*w4.w;
            }
        }
        #pragma unroll
        for (int r = 0; r < 8; ++r)
            dbl[(size_t)(row0 + r)*56 + lane] = acc[r];
    }
}

// ============ dt = softplus(dbl[:, :24] @ dt_w^T + dt_b), 8 rows/block ============
__global__ __launch_bounds__(192)
void k_dt(const float* __restrict__ dbl_f, const float* __restrict__ dbl_r,
          const float* __restrict__ dtw, const float* __restrict__ dtb,
          float* __restrict__ dt_f, float* __restrict__ dt_r)
{
    const float* dbl = blockIdx.y ? dbl_r : dbl_f;
    float*       dt  = blockIdx.y ? dt_r  : dt_f;
    int row0 = blockIdx.x * 8;
    int d = threadIdx.x;
    __shared__ float sd[8][24];
    {
        int lr = threadIdx.x / 24, lc = threadIdx.x % 24;
        sd[lr][lc] = dbl[(size_t)(row0 + lr)*56 + lc];
    }
    __syncthreads();
    float wreg[24];
    #pragma unroll
    for (int r = 0; r < DRK; ++r) wreg[r] = dtw[d*DRK + r];
    float bias = dtb[d];
    #pragma unroll
    for (int rr = 0; rr < 8; ++rr){
        float acc = bias;
        #pragma unroll
        for (int r = 0; r < DRK; ++r) acc += sd[rr][r] * wreg[r];
        dt[(size_t)(row0 + rr)*DI + d] = softplusf(acc);
    }
}

// ============ chunked selective scan — 2 threads/d, LDS-staged inputs ============
__global__ __launch_bounds__(384)
void k_scan_p1(const float* __restrict__ dt_f, const float* __restrict__ dt_r,
               const float* __restrict__ dbl_f, const float* __restrict__ dbl_r,
               const float* __restrict__ xc_f, const float* __restrict__ xc_r,
               const float* __restrict__ A_log,
               float* __restrict__ CA, float* __restrict__ CB)
{
    int ch = blockIdx.x, b = blockIdx.y, dir = blockIdx.z;
    const float* dt  = dir ? dt_r  : dt_f;
    const float* dbl = dir ? dbl_r : dbl_f;
    const float* xc  = dir ? xc_r  : xc_f;
    int t = threadIdx.x;
    int d = t >> 1, sh = (t & 1) * 8;
    float A2[8];
    #pragma unroll
    for (int s = 0; s < 8; ++s) A2[s] = -expf(A_log[d*DST + sh + s]) * 1.44269504f;
    float hB[8];
    #pragma unroll
    for (int s = 0; s < 8; ++s) hB[s] = 0.f;
    float sumdt = 0.f;
    __shared__ float sdt[16][192], sxc[16][192], sB[16][16];
    for (int t0 = 0; t0 < CL/16; ++t0){
        __syncthreads();
        #pragma unroll
        for (int q = 0; q < 2; ++q){
            int idx = t + q*384;
            int j = idx / 48, c4 = (idx % 48)*4;
            int lidx = ch*CL + t0*16 + j;
            int lld = dir ? (LSEQ-1-lidx) : lidx;
            size_t rowbl = (size_t)b*LSEQ + lld;
            *(float4*)&sdt[j][c4] = *(const float4*)&dt[rowbl*DI + c4];
            *(float4*)&sxc[j][c4] = *(const float4*)&xc[rowbl*DI + c4];
        }
        if (t < 256){
            int j = t >> 4, c = t & 15;
            int lidx = ch*CL + t0*16 + j;
            int lld = dir ? (LSEQ-1-lidx) : lidx;
            sB[j][c] = dbl[((size_t)b*LSEQ + lld)*56 + 24 + c];
        }
        __syncthreads();
        #pragma unroll 4
        for (int j = 0; j < 16; ++j){
            float dtv = sdt[j][d];
            float c0  = dtv * sxc[j][d];
            sumdt += dtv;
            #pragma unroll
            for (int s = 0; s < 8; ++s){
                float da = exp2f(dtv * A2[s]);
                hB[s] = da*hB[s] + c0*sB[j][sh + s];
            }
        }
    }
    size_t o = (((size_t)(dir*B_N + b)*NCH + ch)*DI + d)*16 + sh;
    #pragma unroll
    for (int s = 0; s < 8; ++s){
        CA[o + s] = exp2f(sumdt * A2[s]);
        CB[o + s] = hB[s];
    }
}

// p2
__global__ __launch_bounds__(256)
void k_scan_p2(const float* __restrict__ CA, const float* __restrict__ CB,
               float* __restrict__ CH)
{
    int b = blockIdx.y, dir = blockIdx.z;
    int t = blockIdx.x*256 + threadIdx.x;
    size_t base = ((size_t)(dir*B_N + b)*NCH)*(DI*16) + t;
    float h = 0.f;
    for (int c = 0; c < NCH; ++c){
        size_t o = base + (size_t)c*(DI*16);
        CH[o] = h;
        h = CA[o]*h + CB[o];
    }
}

// p3
__global__ __launch_bounds__(384)
void k_scan_p3(const float* __restrict__ dt_f, const float* __restrict__ dt_r,
               const float* __restrict__ dbl_f, const float* __restrict__ dbl_r,
               const float* __restrict__ xc_f, const float* __restrict__ xc_r,
               const float* __restrict__ xz, const float* __restrict__ A_log,
               const float* __restrict__ Dp, const float* __restrict__ CH,
               unsigned short* __restrict__ g_f, unsigned short* __restrict__ g_r)
{
    int ch = blockIdx.x, b = blockIdx.y, dir = blockIdx.z;
    const float* dt  = dir ? dt_r  : dt_f;
    const float* dbl = dir ? dbl_r : dbl_f;
    const float* xc  = dir ? xc_r  : xc_f;
    unsigned short* g = dir ? g_r : g_f;
    int t = threadIdx.x;
    int d = t >> 1, sh = (t & 1) * 8;
    float A2[8];
    #pragma unroll
    for (int s = 0; s < 8; ++s) A2[s] = -expf(A_log[d*DST + sh + s]) * 1.44269504f;
    float Dpd = Dp[d];
    float h[8];
    size_t so = (((size_t)(dir*B_N + b)*NCH + ch)*DI + d)*16 + sh;
    #pragma unroll
    for (int s = 0; s < 8; ++s) h[s] = CH[so + s];
    __shared__ float sdt[16][192], sxc[16][192], szv[16][192], sBC[16][32];
    int lld0 = dir ? (LSEQ-1 - ch*CL) : (ch*CL);
    long gstep = dir ? -(long)DI : (long)DI;
    unsigned short* gp = g + ((size_t)b*LSEQ + lld0)*DI + d;
    for (int t0 = 0; t0 < CL/16; ++t0){
        __syncthreads();
        #pragma unroll
        for (int q = 0; q < 2; ++q){
            int idx = t + q*384;
            int j = idx / 48, c4 = (idx % 48)*4;
            int lidx = ch*CL + t0*16 + j;
            int lld = dir ? (LSEQ-1-lidx) : lidx;
            size_t rowbl = (size_t)b*LSEQ + lld;
            *(float4*)&sdt[j][c4] = *(const float4*)&dt[rowbl*DI + c4];
            *(float4*)&sxc[j][c4] = *(const float4*)&xc[rowbl*DI + c4];
            *(float4*)&szv[j][c4] = *(const float4*)&xz[rowbl*DIMD + DI + c4];
        }
        for (int idx = t; idx < 512; idx += 384){
            int j = idx >> 5, c = idx & 31;
            int lidx = ch*CL + t0*16 + j;
            int lld = dir ? (LSEQ-1-lidx) : lidx;
            sBC[j][c] = dbl[((size_t)b*LSEQ + lld)*56 + 24 + c];
        }
        __syncthreads();
        #pragma unroll 4
        for (int j = 0; j < 16; ++j){
            float dtv = sdt[j][d];
            float xv  = sxc[j][d];
            float c0  = dtv * xv;
            float y = 0.f;
            #pragma unroll
            for (int s = 0; s < 8; ++s){
                float da = exp2f(dtv * A2[s]);
                h[s] = da*h[s] + c0*sBC[j][sh + s];
                y += h[s]*sBC[j][16 + sh + s];
            }
            y += __shfl_xor(y, 1);
            if ((t & 1) == 0){
                float zv = szv[j][d];
                *gp = f2bf((y + Dpd*xv) * siluf(zv));
            }
            gp += gstep;
        }
    }
}

// ============ pooled partial sums over L (for SSA) ============
__global__ __launch_bounds__(384)
void k_pool(const float* __restrict__ m_f, const float* __restrict__ m_r,
            const float* __restrict__ f_flat, float* __restrict__ partial)
{
    int bt = blockIdx.x;
    int sl = blockIdx.y;
    int b = bt / 3, t = bt % 3;
    const float* src = (t == 0) ? m_f : (t == 1) ? m_r : f_flat;
    src += (size_t)b*LSEQ*DIMD + (size_t)sl*(LSEQ/PSL)*DIMD;
    int d = threadIdx.x;
    float sum = 0.f;
    #pragma unroll 8
    for (int l = 0; l < LSEQ/PSL; ++l) sum += src[(size_t)l*DIMD + d];
    partial[((size_t)bt*PSL + sl)*DIMD + d] = sum;
}

// ============ SSA attention weights: softmax over t ============
__global__ __launch_bounds__(384)
void k_ssa(const float* __restrict__ partial, const float* __restrict__ ssaw,
           float* __restrict__ aw)
{
    int b = blockIdx.x;
    int d = threadIdx.x;
    float pooled[3];
    #pragma unroll
    for (int t = 0; t < 3; ++t){
        float sum = 0.f;
        for (int sl = 0; sl < PSL; ++sl) sum += partial[((size_t)(b*3+t)*PSL + sl)*DIMD + d];
        pooled[t] = sum * (1.f/LSEQ);
    }
    float wv[3];
    #pragma unroll
    for (int t = 0; t < 3; ++t)
        wv[t] = pooled[0]*ssaw[d*9 + t*3 + 0] + pooled[1]*ssaw[d*9 + t*3 + 1] + pooled[2]*ssaw[d*9 + t*3 + 2];
    float mx = fmaxf(wv[0], fmaxf(wv[1], wv[2]));
    float e0 = expf(wv[0]-mx), e1 = expf(wv[1]-mx), e2 = expf(wv[2]-mx);
    float inv_ = 1.f / (e0+e1+e2);
    aw[(size_t)(b*3+0)*DIMD + d] = e0*inv_;
    aw[(size_t)(b*3+1)*DIMD + d] = e1*inv_;
    aw[(size_t)(b*3+2)*DIMD + d] = e2*inv_;
}

// ============ depthwise 3x3x3 conv — 2ch/thread, plane-seq, ptr-walk, tanh-gelu ============
__global__ __launch_bounds__(256)
void k_dwconv(const float* __restrict__ h1, const float* __restrict__ dwwT,
              const float* __restrict__ dwb, unsigned short* __restrict__ h2)
{
    int cp = blockIdx.x*256 + threadIdx.x;   // channel pair 0..767
    int c  = cp*2;
    int hy = blockIdx.y;                     // 0..63
    int h = hy >> 1, w0 = (hy & 1) * 16;
    int bnf = blockIdx.z; int b = bnf >> 3, nf = bnf & 7;
    const float2 z2 = {0.f, 0.f};
    float2 acc[16];
    float2 bias = *(const float2*)&dwb[c];
    #pragma unroll
    for (int i = 0; i < 16; ++i) acc[i] = bias;
    const float* basep = h1 + (size_t)b*LSEQ*HID + c;
    #pragma unroll
    for (int dn = 0; dn < 3; ++dn){
        int pn = nf + dn - 1;
        if (pn < 0 || pn >= NFR) continue;   // block-uniform
        float2 wt9[9];
        #pragma unroll
        for (int i = 0; i < 9; ++i) wt9[i] = *(const float2*)&dwwT[(size_t)(dn*9 + i)*HID + c];
        #pragma unroll
        for (int dh = 0; dh < 3; ++dh){
            int ph = h + dh - 1;
            if (ph < 0 || ph >= HH) continue; // block-uniform
            const float* row = basep + ((size_t)pn*1024 + (size_t)ph*32)*HID;
            float2 w_a = (w0 > 0) ? *(const float2*)&row[(size_t)(w0-1)*HID] : z2;
            const float* pc = row + (size_t)w0*HID;
            float2 w_b = *(const float2*)pc;
            pc += HID;
            float2 q0 = wt9[dh*3+0], q1 = wt9[dh*3+1], q2 = wt9[dh*3+2];
            #pragma unroll
            for (int xw = 0; xw < 16; ++xw){
                int wn = w0 + xw + 1;
                float2 w_c = (wn < WW) ? *(const float2*)pc : z2;
                pc += HID;
                acc[xw].x += w_a.x*q0.x + w_b.x*q1.x + w_c.x*q2.x;
                acc[xw].y += w_a.y*q0.y + w_b.y*q1.y + w_c.y*q2.y;
                w_a = w_b; w_b = w_c;
            }
        }
    }
    unsigned short* orow = h2 + ((size_t)b*LSEQ + nf*1024 + h*32 + w0)*HID + c;
    #pragma unroll
    for (int xw = 0; xw < 16; ++xw){
        union { unsigned short u[2]; unsigned int v; } pk;
        pk.u[0] = f2bf(gelut(acc[xw].x));
        pk.u[1] = f2bf(gelut(acc[xw].y));
        *(unsigned int*)(orow + (size_t)xw*HID) = pk.v;
    }
}

// ================================================================
extern "C" void kernel_launch(void* const* d_in, const int* in_sizes, int n_in,
                              void* d_out, int out_size, void* d_ws, size_t ws_size,
                              hipStream_t stream)
{
    const float* x     = (const float*)d_in[0];
    const float* fx    = (const float*)d_in[1];
    const int*   hc    = (const int*)  d_in[2];
    const float* ln1w  = (const float*)d_in[3];
    const float* ln1b  = (const float*)d_in[4];
    const float* inpw  = (const float*)d_in[5];
    const float* convw = (const float*)d_in[6];
    const float* convb = (const float*)d_in[7];
    const float* xpw   = (const float*)d_in[8];
    const float* dtw   = (const float*)d_in[9];
    const float* dtb   = (const float*)d_in[10];
    const float* alog  = (const float*)d_in[11];
    const float* dp    = (const float*)d_in[12];
    const float* outpw = (const float*)d_in[13];
    const float* ssaw  = (const float*)d_in[14];
    const float* ln2w  = (const float*)d_in[15];
    const float* ln2b  = (const float*)d_in[16];
    const float* fc1w  = (const float*)d_in[17];
    const float* fc1b  = (const float*)d_in[18];
    const float* dww   = (const float*)d_in[19];
    const float* dwb   = (const float*)d_in[20];
    const float* fc2w  = (const float*)d_in[21];
    const float* fc2b  = (const float*)d_in[22];

    float* ws = (float*)d_ws;
    float* x_flat = ws + OFF_XFLAT;
    float* f_flat = ws + OFF_FFLAT;
    float* xz     = ws + OFF_XZ;
    float* xc_f   = ws + OFF_XCF;
    float* xc_r   = ws + OFF_XCR;
    float* dbl_f  = ws + OFF_DBLF;
    float* dbl_r  = ws + OFF_DBLR;
    float* dt_f   = ws + OFF_DTF;
    float* dt_r   = ws + OFF_DTR;
    float* m_f    = ws + OFF_MF;
    float* m_r    = ws + OFF_MR_;
    float* h1     = ws + OFF_H1;
    float* pkbuf  = ws + OFF_PK;
    float* xm     = ws + OFF_XM;
    float* part   = ws + OFF_PART;
    float* dwwT   = ws + OFF_PART;
    float* aw     = ws + OFF_AW;
    float* cA     = ws + OFF_CA;
    float* cB     = ws + OFF_CB;
    float* cH     = ws + OFF_CHS;
    float* outm   = ws + OFF_NORM;
    int*   inv    = (int*)(ws + OFF_INV);
    unsigned short* wbf    = (unsigned short*)(ws + OFF_WBF);
    unsigned short* inpw_b = wbf + WB_INP;
    unsigned short* outpw_b= wbf + WB_OUT;
    unsigned short* fc1w_b = wbf + WB_FC1;
    unsigned short* fc2w_b = wbf + WB_FC2;
    unsigned short* nrm_bf = (unsigned short*)(ws + OFF_NORM);
    unsigned short* gf_bf  = (unsigned short*)(ws + OFF_GF);
    unsigned short* gr_bf  = (unsigned short*)(ws + OFF_GR);
    unsigned short* h2_bf  = (unsigned short*)(ws + OFF_H2);
    float* outp   = (float*)d_out;

    // 0. inverse permutation + weight conversions
    k_inv<<<LSEQ/256, 256, 0, stream>>>(hc, inv);
    k_wcvt<<<(int)((WB_TOT + 255)/256), 256, 0, stream>>>(inpw, outpw, fc1w, fc2w, wbf);
    // 1. gather + LN1
    k_gather_ln<<<dim3(32, NFR, B_N*2), 256, 0, stream>>>(x, fx, inv, ln1w, ln1b, x_flat, f_flat, nrm_bf);
    // 2. in_proj
    k_bgemm<0><<<dim3(128,3), 256, 0, stream>>>(nrm_bf, inpw_b, nullptr, nullptr, xz, DIMD, DIMD, DIMD);
    // 3. causal/anti-causal depthwise conv + silu
    k_conv<<<dim3(LSEQ/64, B_N), 256, 0, stream>>>(xz, convw, convb, xc_f, xc_r);
    // 4. x-proj
    k_dbl<<<dim3(MR/64, 2), 256, 0, stream>>>(xc_f, xc_r, xpw, dbl_f, dbl_r);
    // 5. dt projection + softplus
    k_dt<<<dim3(MR/8, 2), 192, 0, stream>>>(dbl_f, dbl_r, dtw, dtb, dt_f, dt_r);
    // 6. chunked selective scans
    k_scan_p1<<<dim3(NCH, B_N, 2), 384, 0, stream>>>(dt_f, dt_r, dbl_f, dbl_r, xc_f, xc_r, alog, cA, cB);
    k_scan_p2<<<dim3(DI*16/256, B_N, 2), 256, 0, stream>>>(cA, cB, cH);
    k_scan_p3<<<dim3(NCH, B_N, 2), 384, 0, stream>>>(dt_f, dt_r, dbl_f, dbl_r, xc_f, xc_r, xz, alog, dp, cH, gf_bf, gr_bf);
    // 7. out_proj
    k_bgemm<0><<<dim3(128,3), 256, 0, stream>>>(gf_bf, outpw_b, nullptr, nullptr, m_f, DIMD, DI, DI);
    k_bgemm<0><<<dim3(128,3), 256, 0, stream>>>(gr_bf, outpw_b, nullptr, nullptr, m_r, DIMD, DI, DI);
    // 8. SSA
    k_pool<<<dim3(6,PSL), 384, 0, stream>>>(m_f, m_r, f_flat, part);
    k_ssa<<<B_N, 384, 0, stream>>>(part, ssaw, aw);
    k_wt<<<(27*HID + 255)/256, 256, 0, stream>>>(dww, dwwT);
    // 9. fused xm + LN2, then MLP
    k_xm_ln<<<MR, 128, 0, stream>>>(x_flat, m_f, m_r, f_flat, aw, ln2w, ln2b, xm, nrm_bf);
    k_bgemm<1><<<dim3(128,12), 256, 0, stream>>>(nrm_bf, fc1w_b, fc1b, nullptr, h1, HID, DIMD, DIMD);
    k_dwconv<<<dim3(3,64,16), 256, 0, stream>>>(h1, dwwT, dwb, h2_bf);
    // 10. fc2 split-K=4
    k_bgemm_sk<<<dim3(128,3,4), 256, 0, stream>>>(h2_bf, fc2w_b, fc2b, xm, outm, pkbuf, DIMD, HID/4, HID);
    // 11. transpose-scatter
    k_scatter<<<dim3(32, NFR, B_N), 256, 0, stream>>>(outm, pkbuf, inv, outp);
}

// Round 17
// 542.282 us; speedup vs baseline: 1.0047x; 1.0047x over previous
//
#include <hip/hip_runtime.h>
#include <cmath>

#define B_N 2
#define NFR 8
#define HH 32
#define WW 32
#define LSEQ 8192
#define DIMD 384
#define DI 192
#define DST 16
#define DRK 24
#define HID 1536
#define MR (B_N*LSEQ)   // 16384 rows

#define NCH 256         // scan chunks
#define CL  (LSEQ/NCH)  // 32 steps per chunk
#define PSL 128         // pool slices

typedef __attribute__((ext_vector_type(8))) short  bf16x8;
typedef __attribute__((ext_vector_type(4))) float  f32x4;
typedef __attribute__((ext_vector_type(8))) unsigned short u16x8;

// ---------------- workspace layout (floats) ----------------
constexpr size_t SZ_BLD = (size_t)MR * DIMD;   // 6291456
constexpr size_t SZ_BLI = (size_t)MR * DI;     // 3145728
constexpr size_t SZ_DBL = (size_t)MR * 56;     // 917504

constexpr size_t OFF_XFLAT = 0;
constexpr size_t OFF_FFLAT = OFF_XFLAT + SZ_BLD;
constexpr size_t OFF_XZ    = OFF_FFLAT + SZ_BLD;
constexpr size_t OFF_XCF   = OFF_XZ + SZ_BLD;
constexpr size_t OFF_XCR   = OFF_XCF + SZ_BLI;
constexpr size_t OFF_H1    = 0;
constexpr size_t OFF_PK    = 0;                     // fc2 split-K partials (3x SZ_BLD)
constexpr size_t OFF_R2    = OFF_XCR + SZ_BLI;      // 25165824
constexpr size_t OFF_DBLF  = OFF_R2;
constexpr size_t OFF_DBLR  = OFF_DBLF + SZ_DBL;
constexpr size_t OFF_DTF   = OFF_DBLR + SZ_DBL;
constexpr size_t OFF_DTR   = OFF_DTF + SZ_BLI;
constexpr size_t OFF_GF    = OFF_DTR + SZ_BLI;      // bf16 g_f
constexpr size_t OFF_GR    = OFF_GF + SZ_BLI;       // bf16 g_r
constexpr size_t OFF_MF    = OFF_GR + SZ_BLI;
constexpr size_t OFF_MR_   = OFF_MF + SZ_BLD;
constexpr size_t OFF_H2    = OFF_R2;                // bf16 h2
constexpr size_t OFF_NORM  = OFF_MR_ + SZ_BLD;      // bf16 normed1/2; later f32 outm
constexpr size_t OFF_XM    = OFF_NORM + SZ_BLD;
constexpr size_t OFF_PART  = OFF_XM + SZ_BLD;       // pool partials; later dwwT
constexpr size_t OFF_AW    = OFF_PART + (size_t)6*PSL*384;
constexpr size_t OFF_INV   = OFF_AW + 2*3*384;      // 8192 ints
constexpr size_t OFF_WBF   = OFF_INV + 8192;        // bf16 weight copies (shorts)
constexpr size_t WB_INP = 0;                         // 384x384   = 147456
constexpr size_t WB_OUT = WB_INP + 147456;           // 384x192   = 73728
constexpr size_t WB_FC1 = WB_OUT + 73728;            // 1536x384  = 589824
constexpr size_t WB_FC2 = WB_FC1 + 589824;           // 384x1536  = 589824
constexpr size_t WB_TOT = WB_FC2 + 589824;
// scan chunk summaries alias dead normed+xm regions:
constexpr size_t SZ_CH   = (size_t)2*B_N*NCH*DI*16;  // 3145728
constexpr size_t OFF_CA  = OFF_NORM;
constexpr size_t OFF_CB  = OFF_CA + SZ_CH;
constexpr size_t OFF_CHS = OFF_CB + SZ_CH;
static_assert(OFF_CHS + SZ_CH <= OFF_PART, "scan summaries overflow");
static_assert(27*HID <= 6*PSL*384, "dwwT overflows part region");

__device__ __forceinline__ float siluf(float x){ return x / (1.f + expf(-x)); }
__device__ __forceinline__ float softplusf(float x){ return x > 20.f ? x : log1pf(expf(x)); }
// tanh-approx GELU (max abs err ~3e-4, below bf16 rounding of the consumer)
__device__ __forceinline__ float gelut(float x){
    float z = 0.7978845608f*(x + 0.044715f*x*x*x);
    float e = __expf(2.f*z);
    float t = 1.f - 2.f/(e + 1.f);
    return 0.5f*x*(1.f + t);
}
__device__ __forceinline__ unsigned short f2bf(float f){
    union { float f; unsigned int u; } v; v.f = f;
    unsigned int u = v.u + 0x7fffu + ((v.u >> 16) & 1u);
    return (unsigned short)(u >> 16);
}

#if __has_builtin(__builtin_amdgcn_global_load_lds)
#define HAVE_GLL 1
__device__ __forceinline__ void gload16(const void* g, void* l){
    __builtin_amdgcn_global_load_lds((const __attribute__((address_space(1))) void*)g,
                                     (__attribute__((address_space(3))) void*)l, 16, 0, 0);
}
#else
#define HAVE_GLL 0
#endif

// ============ inverse permutation ============
__global__ __launch_bounds__(256)
void k_inv(const int* __restrict__ hc, int* __restrict__ inv)
{
    int l = blockIdx.x*256 + threadIdx.x;
    inv[hc[l]] = l;
}

// ============ weight f32->bf16 conversion ============
__global__ __launch_bounds__(256)
void k_wcvt(const float* __restrict__ inpw, const float* __restrict__ outpw,
            const float* __restrict__ fc1w, const float* __restrict__ fc2w,
            unsigned short* __restrict__ wbf)
{
    int idx = blockIdx.x*256 + threadIdx.x;
    if (idx < 147456)                wbf[WB_INP + idx] = f2bf(inpw[idx]);
    else if (idx < 147456+73728)     wbf[WB_OUT + idx-147456] = f2bf(outpw[idx-147456]);
    else if (idx < 221184+589824)    wbf[WB_FC1 + idx-221184] = f2bf(fc1w[idx-221184]);
    else if (idx < 811008+589824)    wbf[WB_FC2 + idx-811008] = f2bf(fc2w[idx-811008]);
}

// ============ dw weight transpose ============
__global__ __launch_bounds__(256)
void k_wt(const float* __restrict__ dww, float* __restrict__ dwwT)
{
    int idx = blockIdx.x*256 + threadIdx.x;
    if (idx < 27*HID){
        int c = idx / 27, i = idx % 27;
        dwwT[i*HID + c] = dww[idx];
    }
}

// ============ gather (transpose-tile) + LayerNorm1, phase-split ============
__global__ __launch_bounds__(256)
void k_gather_ln(const float* __restrict__ x, const float* __restrict__ fx,
                 const int* __restrict__ inv, const float* __restrict__ lw,
                 const float* __restrict__ lb, float* __restrict__ x_flat,
                 float* __restrict__ f_flat, unsigned short* __restrict__ normed)
{
    __shared__ float tile[DIMD*33];
    int hw0 = blockIdx.x * 32;
    int nf  = blockIdx.y;
    int zz  = blockIdx.z;
    int b = zz >> 1, ph = zz & 1;
    int t   = threadIdx.x;
    int hwi = t & 31, dr = t >> 5;
    int w = t >> 6, lane = t & 63;
    const float* src = (ph ? fx : x) + ((size_t)(b*NFR+nf)*DIMD)*1024 + hw0;

    for (int d0 = 0; d0 < DIMD; d0 += 8){
        int d = d0 + dr;
        tile[d*33 + hwi] = src[(size_t)d*1024 + hwi];
    }
    __syncthreads();
    if (ph == 0){
        #pragma unroll
        for (int i = 0; i < 8; ++i){
            int r = w*8 + i;
            int l = inv[nf*1024 + hw0 + r];
            size_t rowo = (size_t)(b*LSEQ + l)*DIMD;
            float v[6]; float s = 0.f, s2 = 0.f;
            #pragma unroll
            for (int c = 0; c < 6; ++c){
                float a = tile[(c*64 + lane)*33 + r];
                v[c] = a; s += a; s2 += a*a;
            }
            #pragma unroll
            for (int o = 1; o < 64; o <<= 1){ s += __shfl_xor(s, o); s2 += __shfl_xor(s2, o); }
            float mean = s * (1.f/DIMD);
            float var  = s2 * (1.f/DIMD) - mean*mean;
            float rs = rsqrtf(var + 1e-5f);
            #pragma unroll
            for (int c = 0; c < 6; ++c){
                int d = c*64 + lane;
                x_flat[rowo + d] = v[c];
                normed[rowo + d] = f2bf((v[c]-mean)*rs*lw[d] + lb[d]);
            }
        }
    } else {
        #pragma unroll
        for (int i = 0; i < 8; ++i){
            int r = w*8 + i;
            int l = inv[nf*1024 + hw0 + r];
            size_t rowo = (size_t)(b*LSEQ + l)*DIMD;
            #pragma unroll
            for (int c = 0; c < 6; ++c)
                f_flat[rowo + c*64 + lane] = tile[(c*64 + lane)*33 + r];
        }
    }
}

// ============ output scatter, sums outm + 3 split-K partials ============
__global__ __launch_bounds__(256)
void k_scatter(const float* __restrict__ outm, const float* __restrict__ pk,
               const int* __restrict__ inv, float* __restrict__ outp)
{
    __shared__ float tile[DIMD*33];
    int hw0 = blockIdx.x * 32;
    int nf  = blockIdx.y;
    int b   = blockIdx.z;
    int t   = threadIdx.x;
    int hwi = t & 31, dr = t >> 5;
    int w = t >> 6, lane = t & 63;
    #pragma unroll
    for (int i = 0; i < 8; ++i){
        int r = w*8 + i;
        int l = inv[nf*1024 + hw0 + r];
        size_t rowo = (size_t)(b*LSEQ + l)*DIMD;
        #pragma unroll
        for (int c = 0; c < 6; ++c){
            size_t o = rowo + c*64 + lane;
            tile[(c*64 + lane)*33 + r] = outm[o] + pk[o] + pk[SZ_BLD + o] + pk[2*SZ_BLD + o];
        }
    }
    __syncthreads();
    float* ob = outp + ((size_t)(b*NFR+nf)*DIMD)*1024 + hw0;
    for (int d0 = 0; d0 < DIMD; d0 += 8){
        int d = d0 + dr;
        ob[(size_t)d*1024 + hwi] = tile[d*33 + hwi];
    }
}

// ============ fused xm + LayerNorm2 ============
__global__ __launch_bounds__(128)
void k_xm_ln(const float* __restrict__ x_flat, const float* __restrict__ m_f,
             const float* __restrict__ m_r, const float* __restrict__ f_flat,
             const float* __restrict__ aw, const float* __restrict__ lw,
             const float* __restrict__ lb, float* __restrict__ xm,
             unsigned short* __restrict__ out)
{
    size_t row = blockIdx.x;
    int b = (int)(row >> 13);
    int t = threadIdx.x;
    float v[3]; float s = 0.f, s2 = 0.f;
    #pragma unroll
    for (int i = 0; i < 3; ++i){
        int d = t + i*128;
        size_t o = row*DIMD + d;
        float a0 = aw[(size_t)(b*3+0)*DIMD + d];
        float a1 = aw[(size_t)(b*3+1)*DIMD + d];
        float a2 = aw[(size_t)(b*3+2)*DIMD + d];
        float val = x_flat[o] + a0*m_f[o] + a1*m_r[o] + a2*f_flat[o];
        xm[o] = val;
        v[i] = val; s += val; s2 += val*val;
    }
    #pragma unroll
    for (int o = 32; o > 0; o >>= 1){ s += __shfl_down(s, o); s2 += __shfl_down(s2, o); }
    __shared__ float sh[4];
    if ((t & 63) == 0){ sh[(t>>6)*2] = s; sh[(t>>6)*2+1] = s2; }
    __syncthreads();
    float S = sh[0] + sh[2], S2 = sh[1] + sh[3];
    float mean = S * (1.f/DIMD);
    float var  = S2 * (1.f/DIMD) - mean*mean;
    float r = rsqrtf(var + 1e-5f);
    #pragma unroll
    for (int i = 0; i < 3; ++i){
        int d = t + i*128;
        out[row*DIMD + d] = f2bf((v[i]-mean)*r*lw[d] + lb[d]);
    }
}

// ============ bf16 MFMA GEMM, both operands bf16, global_load_lds staging ============
template<int EPI>
__global__ __launch_bounds__(256, 2)
void k_bgemm(const unsigned short* __restrict__ A, const unsigned short* __restrict__ Wb,
             const float* __restrict__ bias, const float* __restrict__ add,
             float* __restrict__ C, int N, int Kext, int Kstr)
{
    __shared__ unsigned short As[128*32];
    __shared__ unsigned short Bs[128*32];
    int tid  = threadIdx.x;
    int wid  = tid >> 6, lane = tid & 63;
    int row0 = blockIdx.x * 128, col0 = blockIdx.y * 128;
    int wr = wid >> 1, wc = wid & 1;
    int lr = lane & 15, lg = lane >> 4;

    f32x4 acc[4][4];
    #pragma unroll
    for (int m = 0; m < 4; ++m)
        #pragma unroll
        for (int n = 0; n < 4; ++n) acc[m][n] = (f32x4){0.f,0.f,0.f,0.f};

    int s0 = wid*2048 + lane*16;
    int r0 = s0 >> 6, k0i = (s0 & 63) >> 1;
    int s1 = s0 + 1024;
    int r1 = s1 >> 6, k1i = (s1 & 63) >> 1;
    const unsigned short* Ag0 = A  + (size_t)(row0 + r0)*Kstr + k0i;
    const unsigned short* Ag1 = A  + (size_t)(row0 + r1)*Kstr + k1i;
    const unsigned short* Bg0 = Wb + (size_t)(col0 + r0)*Kstr + k0i;
    const unsigned short* Bg1 = Wb + (size_t)(col0 + r1)*Kstr + k1i;

    const unsigned short* Ab = &As[(wr*64 + lr)*32 + lg*8];
    const unsigned short* Bb = &Bs[(wc*64 + lr)*32 + lg*8];

    for (int k0 = 0; k0 < Kext; k0 += 32){
        if (k0) __syncthreads();
#if HAVE_GLL
        gload16(Ag0, (char*)As + wid*2048);
        gload16(Ag1, (char*)As + wid*2048 + 1024);
        gload16(Bg0, (char*)Bs + wid*2048);
        gload16(Bg1, (char*)Bs + wid*2048 + 1024);
#else
        *(u16x8*)((char*)As + s0) = *(const u16x8*)Ag0;
        *(u16x8*)((char*)As + s1) = *(const u16x8*)Ag1;
        *(u16x8*)((char*)Bs + s0) = *(const u16x8*)Bg0;
        *(u16x8*)((char*)Bs + s1) = *(const u16x8*)Bg1;
#endif
        Ag0 += 32; Ag1 += 32; Bg0 += 32; Bg1 += 32;
        __syncthreads();
        bf16x8 af[4], bfr[4];
        #pragma unroll
        for (int m = 0; m < 4; ++m) af[m]  = *(const bf16x8*)(Ab + m*512);
        #pragma unroll
        for (int n = 0; n < 4; ++n) bfr[n] = *(const bf16x8*)(Bb + n*512);
        #pragma unroll
        for (int m = 0; m < 4; ++m)
            #pragma unroll
            for (int n = 0; n < 4; ++n)
                acc[m][n] = __builtin_amdgcn_mfma_f32_16x16x32_bf16(af[m], bfr[n], acc[m][n], 0, 0, 0);
    }

    #pragma unroll
    for (int m = 0; m < 4; ++m){
        #pragma unroll
        for (int r = 0; r < 4; ++r){
            int row = row0 + wr*64 + m*16 + lg*4 + r;
            #pragma unroll
            for (int n = 0; n < 4; ++n){
                int col = col0 + wc*64 + n*16 + lr;
                float v = acc[m][n][r];
                if (EPI >= 1) v += bias[col];
                if (EPI == 2) v += add[(size_t)row*N + col];
                C[(size_t)row*N + col] = v;
            }
        }
    }
}

// ============ fc2 split-K=4, bf16 both operands ============
__global__ __launch_bounds__(256, 2)
void k_bgemm_sk(const unsigned short* __restrict__ A, const unsigned short* __restrict__ Wb,
                const float* __restrict__ bias, const float* __restrict__ add,
                float* __restrict__ C0, float* __restrict__ PK, int N, int Kq, int Kstr)
{
    __shared__ unsigned short As[128*32];
    __shared__ unsigned short Bs[128*32];
    int tid  = threadIdx.x;
    int wid  = tid >> 6, lane = tid & 63;
    int row0 = blockIdx.x * 128, col0 = blockIdx.y * 128;
    int z = blockIdx.z;
    int kbeg = z * Kq;
    int wr = wid >> 1, wc = wid & 1;
    int lr = lane & 15, lg = lane >> 4;

    f32x4 acc[4][4];
    #pragma unroll
    for (int m = 0; m < 4; ++m)
        #pragma unroll
        for (int n = 0; n < 4; ++n) acc[m][n] = (f32x4){0.f,0.f,0.f,0.f};

    int s0 = wid*2048 + lane*16;
    int r0 = s0 >> 6, k0i = (s0 & 63) >> 1;
    int s1 = s0 + 1024;
    int r1 = s1 >> 6, k1i = (s1 & 63) >> 1;
    const unsigned short* Ag0 = A  + (size_t)(row0 + r0)*Kstr + kbeg + k0i;
    const unsigned short* Ag1 = A  + (size_t)(row0 + r1)*Kstr + kbeg + k1i;
    const unsigned short* Bg0 = Wb + (size_t)(col0 + r0)*Kstr + kbeg + k0i;
    const unsigned short* Bg1 = Wb + (size_t)(col0 + r1)*Kstr + kbeg + k1i;

    const unsigned short* Ab = &As[(wr*64 + lr)*32 + lg*8];
    const unsigned short* Bb = &Bs[(wc*64 + lr)*32 + lg*8];

    for (int k0 = 0; k0 < Kq; k0 += 32){
        if (k0) __syncthreads();
#if HAVE_GLL
        gload16(Ag0, (char*)As + wid*2048);
        gload16(Ag1, (char*)As + wid*2048 + 1024);
        gload16(Bg0, (char*)Bs + wid*2048);
        gload16(Bg1, (char*)Bs + wid*2048 + 1024);
#else
        *(u16x8*)((char*)As + s0) = *(const u16x8*)Ag0;
        *(u16x8*)((char*)As + s1) = *(const u16x8*)Ag1;
        *(u16x8*)((char*)Bs + s0) = *(const u16x8*)Bg0;
        *(u16x8*)((char*)Bs + s1) = *(const u16x8*)Bg1;
#endif
        Ag0 += 32; Ag1 += 32; Bg0 += 32; Bg1 += 32;
        __syncthreads();
        bf16x8 af[4], bfr[4];
        #pragma unroll
        for (int m = 0; m < 4; ++m) af[m]  = *(const bf16x8*)(Ab + m*512);
        #pragma unroll
        for (int n = 0; n < 4; ++n) bfr[n] = *(const bf16x8*)(Bb + n*512);
        #pragma unroll
        for (int m = 0; m < 4; ++m)
            #pragma unroll
            for (int n = 0; n < 4; ++n)
                acc[m][n] = __builtin_amdgcn_mfma_f32_16x16x32_bf16(af[m], bfr[n], acc[m][n], 0, 0, 0);
    }

    float* Cdst = (z == 0) ? C0 : (PK + (size_t)(z-1)*SZ_BLD);
    #pragma unroll
    for (int m = 0; m < 4; ++m){
        #pragma unroll
        for (int r = 0; r < 4; ++r){
            int row = row0 + wr*64 + m*16 + lg*4 + r;
            #pragma unroll
            for (int n = 0; n < 4; ++n){
                int col = col0 + wc*64 + n*16 + lr;
                float v = acc[m][n][r];
                if (z == 0) v += bias[col] + add[(size_t)row*N + col];
                Cdst[(size_t)row*N + col] = v;
            }
        }
    }
}

// ============ causal + anti-causal depthwise conv over L, + silu ============
__global__ __launch_bounds__(256)
void k_conv(const float* __restrict__ xz, const float* __restrict__ cw,
            const float* __restrict__ cb, float* __restrict__ xcf, float* __restrict__ xcr)
{
    const int TL = 64;
    int b = blockIdx.y;
    int l0 = blockIdx.x * TL;
    __shared__ float sx[TL+6][DI];
    for (int idx = threadIdx.x; idx < (TL+6)*DI; idx += 256){
        int r = idx / DI, c = idx % DI;
        int l = l0 + r - 3;
        float v = 0.f;
        if (l >= 0 && l < LSEQ) v = xz[((size_t)b*LSEQ + l)*DIMD + c];
        sx[r][c] = v;
    }
    __syncthreads();
    for (int idx = threadIdx.x; idx < TL*DI; idx += 256){
        int r = idx / DI, c = idx % DI;
        float w0 = cw[c*4+0], w1 = cw[c*4+1], w2 = cw[c*4+2], w3 = cw[c*4+3];
        float bi = cb[c];
        size_t orow = ((size_t)b*LSEQ + l0 + r)*DI + c;
        float af = bi + sx[r][c]*w0 + sx[r+1][c]*w1 + sx[r+2][c]*w2 + sx[r+3][c]*w3;
        xcf[orow] = siluf(af);
        float ar = bi + sx[r+3][c]*w3 + sx[r+4][c]*w2 + sx[r+5][c]*w1 + sx[r+6][c]*w0;
        xcr[orow] = siluf(ar);
    }
}

// ============ dbl = xc @ xproj_w^T  (N=56, K=192), both dirs ============
__global__ __launch_bounds__(256)
void k_dbl(const float* __restrict__ xc_f, const float* __restrict__ xc_r,
           const float* __restrict__ xpw,
           float* __restrict__ dbl_f, float* __restrict__ dbl_r)
{
    const float* xc  = blockIdx.y ? xc_r  : xc_f;
    float*       dbl = blockIdx.y ? dbl_r : dbl_f;
    __shared__ float sw[56*196];
    for (int i = threadIdx.x; i < 56*DI; i += 256){
        int n = i / DI, k = i % DI;
        sw[n*196 + k] = xpw[i];
    }
    __syncthreads();
    int lane = threadIdx.x & 63;
    int wid  = threadIdx.x >> 6;
    if (lane >= 56) return;
    const float* wrow = &sw[lane*196];
    #pragma unroll
    for (int g = 0; g < 2; ++g){
        int row0 = blockIdx.x*64 + g*32 + wid*8;
        const float* xr = xc + (size_t)row0*DI;
        float acc[8];
        #pragma unroll
        for (int r = 0; r < 8; ++r) acc[r] = 0.f;
        for (int k = 0; k < DI; k += 4){
            float4 w4 = *(const float4*)&wrow[k];
            #pragma unroll
            for (int r = 0; r < 8; ++r){
                float4 x4 = *(const float4*)&xr[(size_t)r*DI + k];
                acc[r] += x4.x*w4.x + x4.y*w4.y + x4.z*w4.z + x4.w*w4.w;
            }
        }
        #pragma unroll
        for (int r = 0; r < 8; ++r)
            dbl[(size_t)(row0 + r)*56 + lane] = acc[r];
    }
}

// ============ dt = softplus(dbl[:, :24] @ dt_w^T + dt_b), 8 rows/block ============
__global__ __launch_bounds__(192)
void k_dt(const float* __restrict__ dbl_f, const float* __restrict__ dbl_r,
          const float* __restrict__ dtw, const float* __restrict__ dtb,
          float* __restrict__ dt_f, float* __restrict__ dt_r)
{
    const float* dbl = blockIdx.y ? dbl_r : dbl_f;
    float*       dt  = blockIdx.y ? dt_r  : dt_f;
    int row0 = blockIdx.x * 8;
    int d = threadIdx.x;
    __shared__ float sd[8][24];
    {
        int lr = threadIdx.x / 24, lc = threadIdx.x % 24;
        sd[lr][lc] = dbl[(size_t)(row0 + lr)*56 + lc];
    }
    __syncthreads();
    float wreg[24];
    #pragma unroll
    for (int r = 0; r < DRK; ++r) wreg[r] = dtw[d*DRK + r];
    float bias = dtb[d];
    #pragma unroll
    for (int rr = 0; rr < 8; ++rr){
        float acc = bias;
        #pragma unroll
        for (int r = 0; r < DRK; ++r) acc += sd[rr][r] * wreg[r];
        dt[(size_t)(row0 + rr)*DI + d] = softplusf(acc);
    }
}

// ============ chunked selective scan — 2 threads/d, LDS-staged inputs ============
__global__ __launch_bounds__(384)
void k_scan_p1(const float* __restrict__ dt_f, const float* __restrict__ dt_r,
               const float* __restrict__ dbl_f, const float* __restrict__ dbl_r,
               const float* __restrict__ xc_f, const float* __restrict__ xc_r,
               const float* __restrict__ A_log,
               float* __restrict__ CA, float* __restrict__ CB)
{
    int ch = blockIdx.x, b = blockIdx.y, dir = blockIdx.z;
    const float* dt  = dir ? dt_r  : dt_f;
    const float* dbl = dir ? dbl_r : dbl_f;
    const float* xc  = dir ? xc_r  : xc_f;
    int t = threadIdx.x;
    int d = t >> 1, sh = (t & 1) * 8;
    float A2[8];
    #pragma unroll
    for (int s = 0; s < 8; ++s) A2[s] = -expf(A_log[d*DST + sh + s]) * 1.44269504f;
    float hB[8];
    #pragma unroll
    for (int s = 0; s < 8; ++s) hB[s] = 0.f;
    float sumdt = 0.f;
    __shared__ float sdt[16][192], sxc[16][192], sB[16][16];
    for (int t0 = 0; t0 < CL/16; ++t0){
        __syncthreads();
        #pragma unroll
        for (int q = 0; q < 2; ++q){
            int idx = t + q*384;
            int j = idx / 48, c4 = (idx % 48)*4;
            int lidx = ch*CL + t0*16 + j;
            int lld = dir ? (LSEQ-1-lidx) : lidx;
            size_t rowbl = (size_t)b*LSEQ + lld;
            *(float4*)&sdt[j][c4] = *(const float4*)&dt[rowbl*DI + c4];
            *(float4*)&sxc[j][c4] = *(const float4*)&xc[rowbl*DI + c4];
        }
        if (t < 256){
            int j = t >> 4, c = t & 15;
            int lidx = ch*CL + t0*16 + j;
            int lld = dir ? (LSEQ-1-lidx) : lidx;
            sB[j][c] = dbl[((size_t)b*LSEQ + lld)*56 + 24 + c];
        }
        __syncthreads();
        #pragma unroll 4
        for (int j = 0; j < 16; ++j){
            float dtv = sdt[j][d];
            float c0  = dtv * sxc[j][d];
            sumdt += dtv;
            #pragma unroll
            for (int s = 0; s < 8; ++s){
                float da = exp2f(dtv * A2[s]);
                hB[s] = da*hB[s] + c0*sB[j][sh + s];
            }
        }
    }
    size_t o = (((size_t)(dir*B_N + b)*NCH + ch)*DI + d)*16 + sh;
    #pragma unroll
    for (int s = 0; s < 8; ++s){
        CA[o + s] = exp2f(sumdt * A2[s]);
        CB[o + s] = hB[s];
    }
}

// p2
__global__ __launch_bounds__(256)
void k_scan_p2(const float* __restrict__ CA, const float* __restrict__ CB,
               float* __restrict__ CH)
{
    int b = blockIdx.y, dir = blockIdx.z;
    int t = blockIdx.x*256 + threadIdx.x;
    size_t base = ((size_t)(dir*B_N + b)*NCH)*(DI*16) + t;
    float h = 0.f;
    for (int c = 0; c < NCH; ++c){
        size_t o = base + (size_t)c*(DI*16);
        CH[o] = h;
        h = CA[o]*h + CB[o];
    }
}

// p3
__global__ __launch_bounds__(384)
void k_scan_p3(const float* __restrict__ dt_f, const float* __restrict__ dt_r,
               const float* __restrict__ dbl_f, const float* __restrict__ dbl_r,
               const float* __restrict__ xc_f, const float* __restrict__ xc_r,
               const float* __restrict__ xz, const float* __restrict__ A_log,
               const float* __restrict__ Dp, const float* __restrict__ CH,
               unsigned short* __restrict__ g_f, unsigned short* __restrict__ g_r)
{
    int ch = blockIdx.x, b = blockIdx.y, dir = blockIdx.z;
    const float* dt  = dir ? dt_r  : dt_f;
    const float* dbl = dir ? dbl_r : dbl_f;
    const float* xc  = dir ? xc_r  : xc_f;
    unsigned short* g = dir ? g_r : g_f;
    int t = threadIdx.x;
    int d = t >> 1, sh = (t & 1) * 8;
    float A2[8];
    #pragma unroll
    for (int s = 0; s < 8; ++s) A2[s] = -expf(A_log[d*DST + sh + s]) * 1.44269504f;
    float Dpd = Dp[d];
    float h[8];
    size_t so = (((size_t)(dir*B_N + b)*NCH + ch)*DI + d)*16 + sh;
    #pragma unroll
    for (int s = 0; s < 8; ++s) h[s] = CH[so + s];
    __shared__ float sdt[16][192], sxc[16][192], szv[16][192], sBC[16][32];
    int lld0 = dir ? (LSEQ-1 - ch*CL) : (ch*CL);
    long gstep = dir ? -(long)DI : (long)DI;
    unsigned short* gp = g + ((size_t)b*LSEQ + lld0)*DI + d;
    for (int t0 = 0; t0 < CL/16; ++t0){
        __syncthreads();
        #pragma unroll
        for (int q = 0; q < 2; ++q){
            int idx = t + q*384;
            int j = idx / 48, c4 = (idx % 48)*4;
            int lidx = ch*CL + t0*16 + j;
            int lld = dir ? (LSEQ-1-lidx) : lidx;
            size_t rowbl = (size_t)b*LSEQ + lld;
            *(float4*)&sdt[j][c4] = *(const float4*)&dt[rowbl*DI + c4];
            *(float4*)&sxc[j][c4] = *(const float4*)&xc[rowbl*DI + c4];
            *(float4*)&szv[j][c4] = *(const float4*)&xz[rowbl*DIMD + DI + c4];
        }
        for (int idx = t; idx < 512; idx += 384){
            int j = idx >> 5, c = idx & 31;
            int lidx = ch*CL + t0*16 + j;
            int lld = dir ? (LSEQ-1-lidx) : lidx;
            sBC[j][c] = dbl[((size_t)b*LSEQ + lld)*56 + 24 + c];
        }
        __syncthreads();
        #pragma unroll 4
        for (int j = 0; j < 16; ++j){
            float dtv = sdt[j][d];
            float xv  = sxc[j][d];
            float c0  = dtv * xv;
            float y = 0.f;
            #pragma unroll
            for (int s = 0; s < 8; ++s){
                float da = exp2f(dtv * A2[s]);
                h[s] = da*h[s] + c0*sBC[j][sh + s];
                y += h[s]*sBC[j][16 + sh + s];
            }
            y += __shfl_xor(y, 1);
            if ((t & 1) == 0){
                float zv = szv[j][d];
                *gp = f2bf((y + Dpd*xv) * siluf(zv));
            }
            gp += gstep;
        }
    }
}

// ============ pooled partial sums over L (for SSA) ============
__global__ __launch_bounds__(384)
void k_pool(const float* __restrict__ m_f, const float* __restrict__ m_r,
            const float* __restrict__ f_flat, float* __restrict__ partial)
{
    int bt = blockIdx.x;
    int sl = blockIdx.y;
    int b = bt / 3, t = bt % 3;
    const float* src = (t == 0) ? m_f : (t == 1) ? m_r : f_flat;
    src += (size_t)b*LSEQ*DIMD + (size_t)sl*(LSEQ/PSL)*DIMD;
    int d = threadIdx.x;
    float sum = 0.f;
    #pragma unroll 8
    for (int l = 0; l < LSEQ/PSL; ++l) sum += src[(size_t)l*DIMD + d];
    partial[((size_t)bt*PSL + sl)*DIMD + d] = sum;
}

// ============ SSA attention weights: softmax over t ============
__global__ __launch_bounds__(384)
void k_ssa(const float* __restrict__ partial, const float* __restrict__ ssaw,
           float* __restrict__ aw)
{
    int b = blockIdx.x;
    int d = threadIdx.x;
    float pooled[3];
    #pragma unroll
    for (int t = 0; t < 3; ++t){
        float sum = 0.f;
        for (int sl = 0; sl < PSL; ++sl) sum += partial[((size_t)(b*3+t)*PSL + sl)*DIMD + d];
        pooled[t] = sum * (1.f/LSEQ);
    }
    float wv[3];
    #pragma unroll
    for (int t = 0; t < 3; ++t)
        wv[t] = pooled[0]*ssaw[d*9 + t*3 + 0] + pooled[1]*ssaw[d*9 + t*3 + 1] + pooled[2]*ssaw[d*9 + t*3 + 2];
    float mx = fmaxf(wv[0], fmaxf(wv[1], wv[2]));
    float e0 = expf(wv[0]-mx), e1 = expf(wv[1]-mx), e2 = expf(wv[2]-mx);
    float inv_ = 1.f / (e0+e1+e2);
    aw[(size_t)(b*3+0)*DIMD + d] = e0*inv_;
    aw[(size_t)(b*3+1)*DIMD + d] = e1*inv_;
    aw[(size_t)(b*3+2)*DIMD + d] = e2*inv_;
}

// ============ depthwise 3x3x3 conv — 1ch/thread, plane-seq, ptr-walk, tanh-gelu ============
__global__ __launch_bounds__(256)
void k_dwconv(const float* __restrict__ h1, const float* __restrict__ dwwT,
              const float* __restrict__ dwb, unsigned short* __restrict__ h2)
{
    int c = blockIdx.x*256 + threadIdx.x;    // channel 0..1535
    int hy = blockIdx.y;                     // 0..63
    int h = hy >> 1, w0 = (hy & 1) * 16;
    int bnf = blockIdx.z; int b = bnf >> 3, nf = bnf & 7;
    float acc[16];
    float bias = dwb[c];
    #pragma unroll
    for (int i = 0; i < 16; ++i) acc[i] = bias;
    const float* basep = h1 + (size_t)b*LSEQ*HID + c;
    #pragma unroll
    for (int dn = 0; dn < 3; ++dn){
        int pn = nf + dn - 1;
        if (pn < 0 || pn >= NFR) continue;   // block-uniform
        float wt9[9];
        #pragma unroll
        for (int i = 0; i < 9; ++i) wt9[i] = dwwT[(size_t)(dn*9 + i)*HID + c];
        #pragma unroll
        for (int dh = 0; dh < 3; ++dh){
            int ph = h + dh - 1;
            if (ph < 0 || ph >= HH) continue; // block-uniform
            const float* row = basep + ((size_t)pn*1024 + (size_t)ph*32)*HID;
            float w_a = (w0 > 0) ? row[(size_t)(w0-1)*HID] : 0.f;
            const float* pc = row + (size_t)w0*HID;
            float w_b = *pc; pc += HID;
            float q0 = wt9[dh*3+0], q1 = wt9[dh*3+1], q2 = wt9[dh*3+2];
            #pragma unroll
            for (int xw = 0; xw < 16; ++xw){
                int wn = w0 + xw + 1;
                float w_c = (wn < WW) ? *pc : 0.f;
                pc += HID;
                acc[xw] += w_a*q0 + w_b*q1 + w_c*q2;
                w_a = w_b; w_b = w_c;
            }
        }
    }
    unsigned short* orow = h2 + ((size_t)b*LSEQ + nf*1024 + h*32 + w0)*HID + c;
    #pragma unroll
    for (int xw = 0; xw < 16; ++xw)
        orow[(size_t)xw*HID] = f2bf(gelut(acc[xw]));
}

// ================================================================
extern "C" void kernel_launch(void* const* d_in, const int* in_sizes, int n_in,
                              void* d_out, int out_size, void* d_ws, size_t ws_size,
                              hipStream_t stream)
{
    const float* x     = (const float*)d_in[0];
    const float* fx    = (const float*)d_in[1];
    const int*   hc    = (const int*)  d_in[2];
    const float* ln1w  = (const float*)d_in[3];
    const float* ln1b  = (const float*)d_in[4];
    const float* inpw  = (const float*)d_in[5];
    const float* convw = (const float*)d_in[6];
    const float* convb = (const float*)d_in[7];
    const float* xpw   = (const float*)d_in[8];
    const float* dtw   = (const float*)d_in[9];
    const float* dtb   = (const float*)d_in[10];
    const float* alog  = (const float*)d_in[11];
    const float* dp    = (const float*)d_in[12];
    const float* outpw = (const float*)d_in[13];
    const float* ssaw  = (const float*)d_in[14];
    const float* ln2w  = (const float*)d_in[15];
    const float* ln2b  = (const float*)d_in[16];
    const float* fc1w  = (const float*)d_in[17];
    const float* fc1b  = (const float*)d_in[18];
    const float* dww   = (const float*)d_in[19];
    const float* dwb   = (const float*)d_in[20];
    const float* fc2w  = (const float*)d_in[21];
    const float* fc2b  = (const float*)d_in[22];

    float* ws = (float*)d_ws;
    float* x_flat = ws + OFF_XFLAT;
    float* f_flat = ws + OFF_FFLAT;
    float* xz     = ws + OFF_XZ;
    float* xc_f   = ws + OFF_XCF;
    float* xc_r   = ws + OFF_XCR;
    float* dbl_f  = ws + OFF_DBLF;
    float* dbl_r  = ws + OFF_DBLR;
    float* dt_f   = ws + OFF_DTF;
    float* dt_r   = ws + OFF_DTR;
    float* m_f    = ws + OFF_MF;
    float* m_r    = ws + OFF_MR_;
    float* h1     = ws + OFF_H1;
    float* pkbuf  = ws + OFF_PK;
    float* xm     = ws + OFF_XM;
    float* part   = ws + OFF_PART;
    float* dwwT   = ws + OFF_PART;
    float* aw     = ws + OFF_AW;
    float* cA     = ws + OFF_CA;
    float* cB     = ws + OFF_CB;
    float* cH     = ws + OFF_CHS;
    float* outm   = ws + OFF_NORM;
    int*   inv    = (int*)(ws + OFF_INV);
    unsigned short* wbf    = (unsigned short*)(ws + OFF_WBF);
    unsigned short* inpw_b = wbf + WB_INP;
    unsigned short* outpw_b= wbf + WB_OUT;
    unsigned short* fc1w_b = wbf + WB_FC1;
    unsigned short* fc2w_b = wbf + WB_FC2;
    unsigned short* nrm_bf = (unsigned short*)(ws + OFF_NORM);
    unsigned short* gf_bf  = (unsigned short*)(ws + OFF_GF);
    unsigned short* gr_bf  = (unsigned short*)(ws + OFF_GR);
    unsigned short* h2_bf  = (unsigned short*)(ws + OFF_H2);
    float* outp   = (float*)d_out;

    // 0. inverse permutation + weight conversions
    k_inv<<<LSEQ/256, 256, 0, stream>>>(hc, inv);
    k_wcvt<<<(int)((WB_TOT + 255)/256), 256, 0, stream>>>(inpw, outpw, fc1w, fc2w, wbf);
    // 1. gather + LN1
    k_gather_ln<<<dim3(32, NFR, B_N*2), 256, 0, stream>>>(x, fx, inv, ln1w, ln1b, x_flat, f_flat, nrm_bf);
    // 2. in_proj
    k_bgemm<0><<<dim3(128,3), 256, 0, stream>>>(nrm_bf, inpw_b, nullptr, nullptr, xz, DIMD, DIMD, DIMD);
    // 3. causal/anti-causal depthwise conv + silu
    k_conv<<<dim3(LSEQ/64, B_N), 256, 0, stream>>>(xz, convw, convb, xc_f, xc_r);
    // 4. x-proj
    k_dbl<<<dim3(MR/64, 2), 256, 0, stream>>>(xc_f, xc_r, xpw, dbl_f, dbl_r);
    // 5. dt projection + softplus
    k_dt<<<dim3(MR/8, 2), 192, 0, stream>>>(dbl_f, dbl_r, dtw, dtb, dt_f, dt_r);
    // 6. chunked selective scans
    k_scan_p1<<<dim3(NCH, B_N, 2), 384, 0, stream>>>(dt_f, dt_r, dbl_f, dbl_r, xc_f, xc_r, alog, cA, cB);
    k_scan_p2<<<dim3(DI*16/256, B_N, 2), 256, 0, stream>>>(cA, cB, cH);
    k_scan_p3<<<dim3(NCH, B_N, 2), 384, 0, stream>>>(dt_f, dt_r, dbl_f, dbl_r, xc_f, xc_r, xz, alog, dp, cH, gf_bf, gr_bf);
    // 7. out_proj
    k_bgemm<0><<<dim3(128,3), 256, 0, stream>>>(gf_bf, outpw_b, nullptr, nullptr, m_f, DIMD, DI, DI);
    k_bgemm<0><<<dim3(128,3), 256, 0, stream>>>(gr_bf, outpw_b, nullptr, nullptr, m_r, DIMD, DI, DI);
    // 8. SSA
    k_pool<<<dim3(6,PSL), 384, 0, stream>>>(m_f, m_r, f_flat, part);
    k_ssa<<<B_N, 384, 0, stream>>>(part, ssaw, aw);
    k_wt<<<(27*HID + 255)/256, 256, 0, stream>>>(dww, dwwT);
    // 9. fused xm + LN2, then MLP
    k_xm_ln<<<MR, 128, 0, stream>>>(x_flat, m_f, m_r, f_flat, aw, ln2w, ln2b, xm, nrm_bf);
    k_bgemm<1><<<dim3(128,12), 256, 0, stream>>>(nrm_bf, fc1w_b, fc1b, nullptr, h1, HID, DIMD, DIMD);
    k_dwconv<<<dim3(6,64,16), 256, 0, stream>>>(h1, dwwT, dwb, h2_bf);
    // 10. fc2 split-K=4
    k_bgemm_sk<<<dim3(128,3,4), 256, 0, stream>>>(h2_bf, fc2w_b, fc2b, xm, outm, pkbuf, DIMD, HID/4, HID);
    // 11. transpose-scatter
    k_scatter<<<dim3(32, NFR, B_N), 256, 0, stream>>>(outm, pkbuf, inv, outp);
}

// Round 18
// 523.208 us; speedup vs baseline: 1.0414x; 1.0365x over previous
//
#include <hip/hip_runtime.h>
#include <cmath>

#define B_N 2
#define NFR 8
#define HH 32
#define WW 32
#define LSEQ 8192
#define DIMD 384
#define DI 192
#define DST 16
#define DRK 24
#define HID 1536
#define MR (B_N*LSEQ)   // 16384 rows

#define NCH 256         // scan chunks
#define CL  (LSEQ/NCH)  // 32 steps per chunk
#define PSL 128         // pool slices

typedef __attribute__((ext_vector_type(8))) short  bf16x8;
typedef __attribute__((ext_vector_type(4))) float  f32x4;
typedef __attribute__((ext_vector_type(8))) unsigned short u16x8;

// ---------------- workspace layout (floats) ----------------
constexpr size_t SZ_BLD = (size_t)MR * DIMD;   // 6291456
constexpr size_t SZ_BLI = (size_t)MR * DI;     // 3145728
constexpr size_t SZ_DBL = (size_t)MR * 56;     // 917504

constexpr size_t OFF_XFLAT = 0;
constexpr size_t OFF_FFLAT = OFF_XFLAT + SZ_BLD;
constexpr size_t OFF_XZ    = OFF_FFLAT + SZ_BLD;
constexpr size_t OFF_XCF   = OFF_XZ + SZ_BLD;
constexpr size_t OFF_XCR   = OFF_XCF + SZ_BLI;
constexpr size_t OFF_H1    = 0;
constexpr size_t OFF_PK    = 0;                     // fc2 split-K partials (3x SZ_BLD)
constexpr size_t OFF_R2    = OFF_XCR + SZ_BLI;      // 25165824
constexpr size_t OFF_DBLF  = OFF_R2;
constexpr size_t OFF_DBLR  = OFF_DBLF + SZ_DBL;
constexpr size_t OFF_DTF   = OFF_DBLR + SZ_DBL;
constexpr size_t OFF_DTR   = OFF_DTF + SZ_BLI;
constexpr size_t OFF_GF    = OFF_DTR + SZ_BLI;      // bf16 g_f
constexpr size_t OFF_GR    = OFF_GF + SZ_BLI;       // bf16 g_r
constexpr size_t OFF_MF    = OFF_GR + SZ_BLI;
constexpr size_t OFF_MR_   = OFF_MF + SZ_BLD;
constexpr size_t OFF_H2    = OFF_R2;                // bf16 h2
constexpr size_t OFF_NORM  = OFF_MR_ + SZ_BLD;      // bf16 normed1/2; later f32 outm
constexpr size_t OFF_XM    = OFF_NORM + SZ_BLD;
constexpr size_t OFF_PART  = OFF_XM + SZ_BLD;       // pool partials; later dwwT
constexpr size_t OFF_AW    = OFF_PART + (size_t)6*PSL*384;
constexpr size_t OFF_INV   = OFF_AW + 2*3*384;      // 8192 ints
constexpr size_t OFF_WBF   = OFF_INV + 8192;        // bf16 weight copies (shorts)
constexpr size_t WB_INP = 0;                         // 384x384   = 147456
constexpr size_t WB_OUT = WB_INP + 147456;           // 384x192   = 73728
constexpr size_t WB_FC1 = WB_OUT + 73728;            // 1536x384  = 589824
constexpr size_t WB_FC2 = WB_FC1 + 589824;           // 384x1536  = 589824
constexpr size_t WB_TOT = WB_FC2 + 589824;
// scan chunk summaries alias dead normed+xm regions:
constexpr size_t SZ_CH   = (size_t)2*B_N*NCH*DI*16;  // 3145728
constexpr size_t OFF_CA  = OFF_NORM;
constexpr size_t OFF_CB  = OFF_CA + SZ_CH;
constexpr size_t OFF_CHS = OFF_CB + SZ_CH;
static_assert(OFF_CHS + SZ_CH <= OFF_PART, "scan summaries overflow");
static_assert(27*HID <= 6*PSL*384, "dwwT overflows part region");

__device__ __forceinline__ float siluf(float x){ return x / (1.f + expf(-x)); }
__device__ __forceinline__ float softplusf(float x){ return x > 20.f ? x : log1pf(expf(x)); }
__device__ __forceinline__ float geluf(float x){ return 0.5f * x * (1.f + erff(x * 0.70710678118f)); }
__device__ __forceinline__ unsigned short f2bf(float f){
    union { float f; unsigned int u; } v; v.f = f;
    unsigned int u = v.u + 0x7fffu + ((v.u >> 16) & 1u);
    return (unsigned short)(u >> 16);
}

#if __has_builtin(__builtin_amdgcn_global_load_lds)
#define HAVE_GLL 1
__device__ __forceinline__ void gload16(const void* g, void* l){
    __builtin_amdgcn_global_load_lds((const __attribute__((address_space(1))) void*)g,
                                     (__attribute__((address_space(3))) void*)l, 16, 0, 0);
}
#else
#define HAVE_GLL 0
#endif

// ============ inverse permutation ============
__global__ __launch_bounds__(256)
void k_inv(const int* __restrict__ hc, int* __restrict__ inv)
{
    int l = blockIdx.x*256 + threadIdx.x;
    inv[hc[l]] = l;
}

// ============ weight f32->bf16 conversion ============
__global__ __launch_bounds__(256)
void k_wcvt(const float* __restrict__ inpw, const float* __restrict__ outpw,
            const float* __restrict__ fc1w, const float* __restrict__ fc2w,
            unsigned short* __restrict__ wbf)
{
    int idx = blockIdx.x*256 + threadIdx.x;
    if (idx < 147456)                wbf[WB_INP + idx] = f2bf(inpw[idx]);
    else if (idx < 147456+73728)     wbf[WB_OUT + idx-147456] = f2bf(outpw[idx-147456]);
    else if (idx < 221184+589824)    wbf[WB_FC1 + idx-221184] = f2bf(fc1w[idx-221184]);
    else if (idx < 811008+589824)    wbf[WB_FC2 + idx-811008] = f2bf(fc2w[idx-811008]);
}

// ============ dw weight transpose ============
__global__ __launch_bounds__(256)
void k_wt(const float* __restrict__ dww, float* __restrict__ dwwT)
{
    int idx = blockIdx.x*256 + threadIdx.x;
    if (idx < 27*HID){
        int c = idx / 27, i = idx % 27;
        dwwT[i*HID + c] = dww[idx];
    }
}

// ============ gather (transpose-tile) + LayerNorm1, phase-split ============
__global__ __launch_bounds__(256)
void k_gather_ln(const float* __restrict__ x, const float* __restrict__ fx,
                 const int* __restrict__ inv, const float* __restrict__ lw,
                 const float* __restrict__ lb, float* __restrict__ x_flat,
                 float* __restrict__ f_flat, unsigned short* __restrict__ normed)
{
    __shared__ float tile[DIMD*33];
    int hw0 = blockIdx.x * 32;
    int nf  = blockIdx.y;
    int zz  = blockIdx.z;
    int b = zz >> 1, ph = zz & 1;
    int t   = threadIdx.x;
    int hwi = t & 31, dr = t >> 5;
    int w = t >> 6, lane = t & 63;
    const float* src = (ph ? fx : x) + ((size_t)(b*NFR+nf)*DIMD)*1024 + hw0;

    for (int d0 = 0; d0 < DIMD; d0 += 8){
        int d = d0 + dr;
        tile[d*33 + hwi] = src[(size_t)d*1024 + hwi];
    }
    __syncthreads();
    if (ph == 0){
        #pragma unroll
        for (int i = 0; i < 8; ++i){
            int r = w*8 + i;
            int l = inv[nf*1024 + hw0 + r];
            size_t rowo = (size_t)(b*LSEQ + l)*DIMD;
            float v[6]; float s = 0.f, s2 = 0.f;
            #pragma unroll
            for (int c = 0; c < 6; ++c){
                float a = tile[(c*64 + lane)*33 + r];
                v[c] = a; s += a; s2 += a*a;
            }
            #pragma unroll
            for (int o = 1; o < 64; o <<= 1){ s += __shfl_xor(s, o); s2 += __shfl_xor(s2, o); }
            float mean = s * (1.f/DIMD);
            float var  = s2 * (1.f/DIMD) - mean*mean;
            float rs = rsqrtf(var + 1e-5f);
            #pragma unroll
            for (int c = 0; c < 6; ++c){
                int d = c*64 + lane;
                x_flat[rowo + d] = v[c];
                normed[rowo + d] = f2bf((v[c]-mean)*rs*lw[d] + lb[d]);
            }
        }
    } else {
        #pragma unroll
        for (int i = 0; i < 8; ++i){
            int r = w*8 + i;
            int l = inv[nf*1024 + hw0 + r];
            size_t rowo = (size_t)(b*LSEQ + l)*DIMD;
            #pragma unroll
            for (int c = 0; c < 6; ++c)
                f_flat[rowo + c*64 + lane] = tile[(c*64 + lane)*33 + r];
        }
    }
}

// ============ output scatter, sums outm + 3 split-K partials ============
__global__ __launch_bounds__(256)
void k_scatter(const float* __restrict__ outm, const float* __restrict__ pk,
               const int* __restrict__ inv, float* __restrict__ outp)
{
    __shared__ float tile[DIMD*33];
    int hw0 = blockIdx.x * 32;
    int nf  = blockIdx.y;
    int b   = blockIdx.z;
    int t   = threadIdx.x;
    int hwi = t & 31, dr = t >> 5;
    int w = t >> 6, lane = t & 63;
    #pragma unroll
    for (int i = 0; i < 8; ++i){
        int r = w*8 + i;
        int l = inv[nf*1024 + hw0 + r];
        size_t rowo = (size_t)(b*LSEQ + l)*DIMD;
        #pragma unroll
        for (int c = 0; c < 6; ++c){
            size_t o = rowo + c*64 + lane;
            tile[(c*64 + lane)*33 + r] = outm[o] + pk[o] + pk[SZ_BLD + o] + pk[2*SZ_BLD + o];
        }
    }
    __syncthreads();
    float* ob = outp + ((size_t)(b*NFR+nf)*DIMD)*1024 + hw0;
    for (int d0 = 0; d0 < DIMD; d0 += 8){
        int d = d0 + dr;
        ob[(size_t)d*1024 + hwi] = tile[d*33 + hwi];
    }
}

// ============ fused xm + LayerNorm2 ============
__global__ __launch_bounds__(128)
void k_xm_ln(const float* __restrict__ x_flat, const float* __restrict__ m_f,
             const float* __restrict__ m_r, const float* __restrict__ f_flat,
             const float* __restrict__ aw, const float* __restrict__ lw,
             const float* __restrict__ lb, float* __restrict__ xm,
             unsigned short* __restrict__ out)
{
    size_t row = blockIdx.x;
    int b = (int)(row >> 13);
    int t = threadIdx.x;
    float v[3]; float s = 0.f, s2 = 0.f;
    #pragma unroll
    for (int i = 0; i < 3; ++i){
        int d = t + i*128;
        size_t o = row*DIMD + d;
        float a0 = aw[(size_t)(b*3+0)*DIMD + d];
        float a1 = aw[(size_t)(b*3+1)*DIMD + d];
        float a2 = aw[(size_t)(b*3+2)*DIMD + d];
        float val = x_flat[o] + a0*m_f[o] + a1*m_r[o] + a2*f_flat[o];
        xm[o] = val;
        v[i] = val; s += val; s2 += val*val;
    }
    #pragma unroll
    for (int o = 32; o > 0; o >>= 1){ s += __shfl_down(s, o); s2 += __shfl_down(s2, o); }
    __shared__ float sh[4];
    if ((t & 63) == 0){ sh[(t>>6)*2] = s; sh[(t>>6)*2+1] = s2; }
    __syncthreads();
    float S = sh[0] + sh[2], S2 = sh[1] + sh[3];
    float mean = S * (1.f/DIMD);
    float var  = S2 * (1.f/DIMD) - mean*mean;
    float r = rsqrtf(var + 1e-5f);
    #pragma unroll
    for (int i = 0; i < 3; ++i){
        int d = t + i*128;
        out[row*DIMD + d] = f2bf((v[i]-mean)*r*lw[d] + lb[d]);
    }
}

// ============ bf16 MFMA GEMM, both operands bf16, global_load_lds staging ============
template<int EPI>
__global__ __launch_bounds__(256, 2)
void k_bgemm(const unsigned short* __restrict__ A, const unsigned short* __restrict__ Wb,
             const float* __restrict__ bias, const float* __restrict__ add,
             float* __restrict__ C, int N, int Kext, int Kstr)
{
    __shared__ unsigned short As[128*32];
    __shared__ unsigned short Bs[128*32];
    int tid  = threadIdx.x;
    int wid  = tid >> 6, lane = tid & 63;
    int row0 = blockIdx.x * 128, col0 = blockIdx.y * 128;
    int wr = wid >> 1, wc = wid & 1;
    int lr = lane & 15, lg = lane >> 4;

    f32x4 acc[4][4];
    #pragma unroll
    for (int m = 0; m < 4; ++m)
        #pragma unroll
        for (int n = 0; n < 4; ++n) acc[m][n] = (f32x4){0.f,0.f,0.f,0.f};

    int s0 = wid*2048 + lane*16;
    int r0 = s0 >> 6, k0i = (s0 & 63) >> 1;
    int s1 = s0 + 1024;
    int r1 = s1 >> 6, k1i = (s1 & 63) >> 1;
    const unsigned short* Ag0 = A  + (size_t)(row0 + r0)*Kstr + k0i;
    const unsigned short* Ag1 = A  + (size_t)(row0 + r1)*Kstr + k1i;
    const unsigned short* Bg0 = Wb + (size_t)(col0 + r0)*Kstr + k0i;
    const unsigned short* Bg1 = Wb + (size_t)(col0 + r1)*Kstr + k1i;

    const unsigned short* Ab = &As[(wr*64 + lr)*32 + lg*8];
    const unsigned short* Bb = &Bs[(wc*64 + lr)*32 + lg*8];

    for (int k0 = 0; k0 < Kext; k0 += 32){
        if (k0) __syncthreads();
#if HAVE_GLL
        gload16(Ag0, (char*)As + wid*2048);
        gload16(Ag1, (char*)As + wid*2048 + 1024);
        gload16(Bg0, (char*)Bs + wid*2048);
        gload16(Bg1, (char*)Bs + wid*2048 + 1024);
#else
        *(u16x8*)((char*)As + s0) = *(const u16x8*)Ag0;
        *(u16x8*)((char*)As + s1) = *(const u16x8*)Ag1;
        *(u16x8*)((char*)Bs + s0) = *(const u16x8*)Bg0;
        *(u16x8*)((char*)Bs + s1) = *(const u16x8*)Bg1;
#endif
        Ag0 += 32; Ag1 += 32; Bg0 += 32; Bg1 += 32;
        __syncthreads();
        bf16x8 af[4], bfr[4];
        #pragma unroll
        for (int m = 0; m < 4; ++m) af[m]  = *(const bf16x8*)(Ab + m*512);
        #pragma unroll
        for (int n = 0; n < 4; ++n) bfr[n] = *(const bf16x8*)(Bb + n*512);
        #pragma unroll
        for (int m = 0; m < 4; ++m)
            #pragma unroll
            for (int n = 0; n < 4; ++n)
                acc[m][n] = __builtin_amdgcn_mfma_f32_16x16x32_bf16(af[m], bfr[n], acc[m][n], 0, 0, 0);
    }

    #pragma unroll
    for (int m = 0; m < 4; ++m){
        #pragma unroll
        for (int r = 0; r < 4; ++r){
            int row = row0 + wr*64 + m*16 + lg*4 + r;
            #pragma unroll
            for (int n = 0; n < 4; ++n){
                int col = col0 + wc*64 + n*16 + lr;
                float v = acc[m][n][r];
                if (EPI >= 1) v += bias[col];
                if (EPI == 2) v += add[(size_t)row*N + col];
                C[(size_t)row*N + col] = v;
            }
        }
    }
}

// ============ fc2 split-K=4, bf16 both operands ============
__global__ __launch_bounds__(256, 2)
void k_bgemm_sk(const unsigned short* __restrict__ A, const unsigned short* __restrict__ Wb,
                const float* __restrict__ bias, const float* __restrict__ add,
                float* __restrict__ C0, float* __restrict__ PK, int N, int Kq, int Kstr)
{
    __shared__ unsigned short As[128*32];
    __shared__ unsigned short Bs[128*32];
    int tid  = threadIdx.x;
    int wid  = tid >> 6, lane = tid & 63;
    int row0 = blockIdx.x * 128, col0 = blockIdx.y * 128;
    int z = blockIdx.z;
    int kbeg = z * Kq;
    int wr = wid >> 1, wc = wid & 1;
    int lr = lane & 15, lg = lane >> 4;

    f32x4 acc[4][4];
    #pragma unroll
    for (int m = 0; m < 4; ++m)
        #pragma unroll
        for (int n = 0; n < 4; ++n) acc[m][n] = (f32x4){0.f,0.f,0.f,0.f};

    int s0 = wid*2048 + lane*16;
    int r0 = s0 >> 6, k0i = (s0 & 63) >> 1;
    int s1 = s0 + 1024;
    int r1 = s1 >> 6, k1i = (s1 & 63) >> 1;
    const unsigned short* Ag0 = A  + (size_t)(row0 + r0)*Kstr + kbeg + k0i;
    const unsigned short* Ag1 = A  + (size_t)(row0 + r1)*Kstr + kbeg + k1i;
    const unsigned short* Bg0 = Wb + (size_t)(col0 + r0)*Kstr + kbeg + k0i;
    const unsigned short* Bg1 = Wb + (size_t)(col0 + r1)*Kstr + kbeg + k1i;

    const unsigned short* Ab = &As[(wr*64 + lr)*32 + lg*8];
    const unsigned short* Bb = &Bs[(wc*64 + lr)*32 + lg*8];

    for (int k0 = 0; k0 < Kq; k0 += 32){
        if (k0) __syncthreads();
#if HAVE_GLL
        gload16(Ag0, (char*)As + wid*2048);
        gload16(Ag1, (char*)As + wid*2048 + 1024);
        gload16(Bg0, (char*)Bs + wid*2048);
        gload16(Bg1, (char*)Bs + wid*2048 + 1024);
#else
        *(u16x8*)((char*)As + s0) = *(const u16x8*)Ag0;
        *(u16x8*)((char*)As + s1) = *(const u16x8*)Ag1;
        *(u16x8*)((char*)Bs + s0) = *(const u16x8*)Bg0;
        *(u16x8*)((char*)Bs + s1) = *(const u16x8*)Bg1;
#endif
        Ag0 += 32; Ag1 += 32; Bg0 += 32; Bg1 += 32;
        __syncthreads();
        bf16x8 af[4], bfr[4];
        #pragma unroll
        for (int m = 0; m < 4; ++m) af[m]  = *(const bf16x8*)(Ab + m*512);
        #pragma unroll
        for (int n = 0; n < 4; ++n) bfr[n] = *(const bf16x8*)(Bb + n*512);
        #pragma unroll
        for (int m = 0; m < 4; ++m)
            #pragma unroll
            for (int n = 0; n < 4; ++n)
                acc[m][n] = __builtin_amdgcn_mfma_f32_16x16x32_bf16(af[m], bfr[n], acc[m][n], 0, 0, 0);
    }

    float* Cdst = (z == 0) ? C0 : (PK + (size_t)(z-1)*SZ_BLD);
    #pragma unroll
    for (int m = 0; m < 4; ++m){
        #pragma unroll
        for (int r = 0; r < 4; ++r){
            int row = row0 + wr*64 + m*16 + lg*4 + r;
            #pragma unroll
            for (int n = 0; n < 4; ++n){
                int col = col0 + wc*64 + n*16 + lr;
                float v = acc[m][n][r];
                if (z == 0) v += bias[col] + add[(size_t)row*N + col];
                Cdst[(size_t)row*N + col] = v;
            }
        }
    }
}

// ============ causal + anti-causal depthwise conv over L, + silu ============
__global__ __launch_bounds__(256)
void k_conv(const float* __restrict__ xz, const float* __restrict__ cw,
            const float* __restrict__ cb, float* __restrict__ xcf, float* __restrict__ xcr)
{
    const int TL = 64;
    int b = blockIdx.y;
    int l0 = blockIdx.x * TL;
    __shared__ float sx[TL+6][DI];
    for (int idx = threadIdx.x; idx < (TL+6)*DI; idx += 256){
        int r = idx / DI, c = idx % DI;
        int l = l0 + r - 3;
        float v = 0.f;
        if (l >= 0 && l < LSEQ) v = xz[((size_t)b*LSEQ + l)*DIMD + c];
        sx[r][c] = v;
    }
    __syncthreads();
    for (int idx = threadIdx.x; idx < TL*DI; idx += 256){
        int r = idx / DI, c = idx % DI;
        float w0 = cw[c*4+0], w1 = cw[c*4+1], w2 = cw[c*4+2], w3 = cw[c*4+3];
        float bi = cb[c];
        size_t orow = ((size_t)b*LSEQ + l0 + r)*DI + c;
        float af = bi + sx[r][c]*w0 + sx[r+1][c]*w1 + sx[r+2][c]*w2 + sx[r+3][c]*w3;
        xcf[orow] = siluf(af);
        float ar = bi + sx[r+3][c]*w3 + sx[r+4][c]*w2 + sx[r+5][c]*w1 + sx[r+6][c]*w0;
        xcr[orow] = siluf(ar);
    }
}

// ============ dbl = xc @ xproj_w^T  (N=56, K=192), both dirs ============
__global__ __launch_bounds__(256)
void k_dbl(const float* __restrict__ xc_f, const float* __restrict__ xc_r,
           const float* __restrict__ xpw,
           float* __restrict__ dbl_f, float* __restrict__ dbl_r)
{
    const float* xc  = blockIdx.y ? xc_r  : xc_f;
    float*       dbl = blockIdx.y ? dbl_r : dbl_f;
    __shared__ float sw[56*196];
    for (int i = threadIdx.x; i < 56*DI; i += 256){
        int n = i / DI, k = i % DI;
        sw[n*196 + k] = xpw[i];
    }
    __syncthreads();
    int lane = threadIdx.x & 63;
    int wid  = threadIdx.x >> 6;
    if (lane >= 56) return;
    const float* wrow = &sw[lane*196];
    #pragma unroll
    for (int g = 0; g < 2; ++g){
        int row0 = blockIdx.x*64 + g*32 + wid*8;
        const float* xr = xc + (size_t)row0*DI;
        float acc[8];
        #pragma unroll
        for (int r = 0; r < 8; ++r) acc[r] = 0.f;
        for (int k = 0; k < DI; k += 4){
            float4 w4 = *(const float4*)&wrow[k];
            #pragma unroll
            for (int r = 0; r < 8; ++r){
                float4 x4 = *(const float4*)&xr[(size_t)r*DI + k];
                acc[r] += x4.x*w4.x + x4.y*w4.y + x4.z*w4.z + x4.w*w4.w;
            }
        }
        #pragma unroll
        for (int r = 0; r < 8; ++r)
            dbl[(size_t)(row0 + r)*56 + lane] = acc[r];
    }
}

// ============ dt = softplus(dbl[:, :24] @ dt_w^T + dt_b), 8 rows/block ============
__global__ __launch_bounds__(192)
void k_dt(const float* __restrict__ dbl_f, const float* __restrict__ dbl_r,
          const float* __restrict__ dtw, const float* __restrict__ dtb,
          float* __restrict__ dt_f, float* __restrict__ dt_r)
{
    const float* dbl = blockIdx.y ? dbl_r : dbl_f;
    float*       dt  = blockIdx.y ? dt_r  : dt_f;
    int row0 = blockIdx.x * 8;
    int d = threadIdx.x;
    __shared__ float sd[8][24];
    {
        int lr = threadIdx.x / 24, lc = threadIdx.x % 24;
        sd[lr][lc] = dbl[(size_t)(row0 + lr)*56 + lc];
    }
    __syncthreads();
    float wreg[24];
    #pragma unroll
    for (int r = 0; r < DRK; ++r) wreg[r] = dtw[d*DRK + r];
    float bias = dtb[d];
    #pragma unroll
    for (int rr = 0; rr < 8; ++rr){
        float acc = bias;
        #pragma unroll
        for (int r = 0; r < DRK; ++r) acc += sd[rr][r] * wreg[r];
        dt[(size_t)(row0 + rr)*DI + d] = softplusf(acc);
    }
}

// ============ chunked selective scan — 2 threads/d, LDS-staged inputs ============
__global__ __launch_bounds__(384)
void k_scan_p1(const float* __restrict__ dt_f, const float* __restrict__ dt_r,
               const float* __restrict__ dbl_f, const float* __restrict__ dbl_r,
               const float* __restrict__ xc_f, const float* __restrict__ xc_r,
               const float* __restrict__ A_log,
               float* __restrict__ CA, float* __restrict__ CB)
{
    int ch = blockIdx.x, b = blockIdx.y, dir = blockIdx.z;
    const float* dt  = dir ? dt_r  : dt_f;
    const float* dbl = dir ? dbl_r : dbl_f;
    const float* xc  = dir ? xc_r  : xc_f;
    int t = threadIdx.x;
    int d = t >> 1, sh = (t & 1) * 8;
    float A2[8];
    #pragma unroll
    for (int s = 0; s < 8; ++s) A2[s] = -expf(A_log[d*DST + sh + s]) * 1.44269504f;
    float hB[8];
    #pragma unroll
    for (int s = 0; s < 8; ++s) hB[s] = 0.f;
    float sumdt = 0.f;
    __shared__ float sdt[16][192], sxc[16][192], sB[16][16];
    for (int t0 = 0; t0 < CL/16; ++t0){
        __syncthreads();
        #pragma unroll
        for (int q = 0; q < 2; ++q){
            int idx = t + q*384;
            int j = idx / 48, c4 = (idx % 48)*4;
            int lidx = ch*CL + t0*16 + j;
            int lld = dir ? (LSEQ-1-lidx) : lidx;
            size_t rowbl = (size_t)b*LSEQ + lld;
            *(float4*)&sdt[j][c4] = *(const float4*)&dt[rowbl*DI + c4];
            *(float4*)&sxc[j][c4] = *(const float4*)&xc[rowbl*DI + c4];
        }
        if (t < 256){
            int j = t >> 4, c = t & 15;
            int lidx = ch*CL + t0*16 + j;
            int lld = dir ? (LSEQ-1-lidx) : lidx;
            sB[j][c] = dbl[((size_t)b*LSEQ + lld)*56 + 24 + c];
        }
        __syncthreads();
        #pragma unroll 4
        for (int j = 0; j < 16; ++j){
            float dtv = sdt[j][d];
            float c0  = dtv * sxc[j][d];
            sumdt += dtv;
            #pragma unroll
            for (int s = 0; s < 8; ++s){
                float da = exp2f(dtv * A2[s]);
                hB[s] = da*hB[s] + c0*sB[j][sh + s];
            }
        }
    }
    size_t o = (((size_t)(dir*B_N + b)*NCH + ch)*DI + d)*16 + sh;
    #pragma unroll
    for (int s = 0; s < 8; ++s){
        CA[o + s] = exp2f(sumdt * A2[s]);
        CB[o + s] = hB[s];
    }
}

// p2
__global__ __launch_bounds__(256)
void k_scan_p2(const float* __restrict__ CA, const float* __restrict__ CB,
               float* __restrict__ CH)
{
    int b = blockIdx.y, dir = blockIdx.z;
    int t = blockIdx.x*256 + threadIdx.x;
    size_t base = ((size_t)(dir*B_N + b)*NCH)*(DI*16) + t;
    float h = 0.f;
    for (int c = 0; c < NCH; ++c){
        size_t o = base + (size_t)c*(DI*16);
        CH[o] = h;
        h = CA[o]*h + CB[o];
    }
}

// p3
__global__ __launch_bounds__(384)
void k_scan_p3(const float* __restrict__ dt_f, const float* __restrict__ dt_r,
               const float* __restrict__ dbl_f, const float* __restrict__ dbl_r,
               const float* __restrict__ xc_f, const float* __restrict__ xc_r,
               const float* __restrict__ xz, const float* __restrict__ A_log,
               const float* __restrict__ Dp, const float* __restrict__ CH,
               unsigned short* __restrict__ g_f, unsigned short* __restrict__ g_r)
{
    int ch = blockIdx.x, b = blockIdx.y, dir = blockIdx.z;
    const float* dt  = dir ? dt_r  : dt_f;
    const float* dbl = dir ? dbl_r : dbl_f;
    const float* xc  = dir ? xc_r  : xc_f;
    unsigned short* g = dir ? g_r : g_f;
    int t = threadIdx.x;
    int d = t >> 1, sh = (t & 1) * 8;
    float A2[8];
    #pragma unroll
    for (int s = 0; s < 8; ++s) A2[s] = -expf(A_log[d*DST + sh + s]) * 1.44269504f;
    float Dpd = Dp[d];
    float h[8];
    size_t so = (((size_t)(dir*B_N + b)*NCH + ch)*DI + d)*16 + sh;
    #pragma unroll
    for (int s = 0; s < 8; ++s) h[s] = CH[so + s];
    __shared__ float sdt[16][192], sxc[16][192], szv[16][192], sBC[16][32];
    int lld0 = dir ? (LSEQ-1 - ch*CL) : (ch*CL);
    long gstep = dir ? -(long)DI : (long)DI;
    unsigned short* gp = g + ((size_t)b*LSEQ + lld0)*DI + d;
    for (int t0 = 0; t0 < CL/16; ++t0){
        __syncthreads();
        #pragma unroll
        for (int q = 0; q < 2; ++q){
            int idx = t + q*384;
            int j = idx / 48, c4 = (idx % 48)*4;
            int lidx = ch*CL + t0*16 + j;
            int lld = dir ? (LSEQ-1-lidx) : lidx;
            size_t rowbl = (size_t)b*LSEQ + lld;
            *(float4*)&sdt[j][c4] = *(const float4*)&dt[rowbl*DI + c4];
            *(float4*)&sxc[j][c4] = *(const float4*)&xc[rowbl*DI + c4];
            *(float4*)&szv[j][c4] = *(const float4*)&xz[rowbl*DIMD + DI + c4];
        }
        for (int idx = t; idx < 512; idx += 384){
            int j = idx >> 5, c = idx & 31;
            int lidx = ch*CL + t0*16 + j;
            int lld = dir ? (LSEQ-1-lidx) : lidx;
            sBC[j][c] = dbl[((size_t)b*LSEQ + lld)*56 + 24 + c];
        }
        __syncthreads();
        #pragma unroll 4
        for (int j = 0; j < 16; ++j){
            float dtv = sdt[j][d];
            float xv  = sxc[j][d];
            float c0  = dtv * xv;
            float y = 0.f;
            #pragma unroll
            for (int s = 0; s < 8; ++s){
                float da = exp2f(dtv * A2[s]);
                h[s] = da*h[s] + c0*sBC[j][sh + s];
                y += h[s]*sBC[j][16 + sh + s];
            }
            y += __shfl_xor(y, 1);
            if ((t & 1) == 0){
                float zv = szv[j][d];
                *gp = f2bf((y + Dpd*xv) * siluf(zv));
            }
            gp += gstep;
        }
    }
}

// ============ pooled partial sums over L (for SSA) ============
__global__ __launch_bounds__(384)
void k_pool(const float* __restrict__ m_f, const float* __restrict__ m_r,
            const float* __restrict__ f_flat, float* __restrict__ partial)
{
    int bt = blockIdx.x;
    int sl = blockIdx.y;
    int b = bt / 3, t = bt % 3;
    const float* src = (t == 0) ? m_f : (t == 1) ? m_r : f_flat;
    src += (size_t)b*LSEQ*DIMD + (size_t)sl*(LSEQ/PSL)*DIMD;
    int d = threadIdx.x;
    float sum = 0.f;
    #pragma unroll 8
    for (int l = 0; l < LSEQ/PSL; ++l) sum += src[(size_t)l*DIMD + d];
    partial[((size_t)bt*PSL + sl)*DIMD + d] = sum;
}

// ============ SSA attention weights: softmax over t ============
__global__ __launch_bounds__(384)
void k_ssa(const float* __restrict__ partial, const float* __restrict__ ssaw,
           float* __restrict__ aw)
{
    int b = blockIdx.x;
    int d = threadIdx.x;
    float pooled[3];
    #pragma unroll
    for (int t = 0; t < 3; ++t){
        float sum = 0.f;
        for (int sl = 0; sl < PSL; ++sl) sum += partial[((size_t)(b*3+t)*PSL + sl)*DIMD + d];
        pooled[t] = sum * (1.f/LSEQ);
    }
    float wv[3];
    #pragma unroll
    for (int t = 0; t < 3; ++t)
        wv[t] = pooled[0]*ssaw[d*9 + t*3 + 0] + pooled[1]*ssaw[d*9 + t*3 + 1] + pooled[2]*ssaw[d*9 + t*3 + 2];
    float mx = fmaxf(wv[0], fmaxf(wv[1], wv[2]));
    float e0 = expf(wv[0]-mx), e1 = expf(wv[1]-mx), e2 = expf(wv[2]-mx);
    float inv_ = 1.f / (e0+e1+e2);
    aw[(size_t)(b*3+0)*DIMD + d] = e0*inv_;
    aw[(size_t)(b*3+1)*DIMD + d] = e1*inv_;
    aw[(size_t)(b*3+2)*DIMD + d] = e2*inv_;
}

// ============ depthwise 3x3x3 conv — round-15 exact: plane-seq, indexed, erff ============
__global__ __launch_bounds__(256)
void k_dwconv(const float* __restrict__ h1, const float* __restrict__ dwwT,
              const float* __restrict__ dwb, unsigned short* __restrict__ h2)
{
    int c = blockIdx.x*256 + threadIdx.x;    // channel 0..1535
    int hy = blockIdx.y;                     // 0..63
    int h = hy >> 1, w0 = (hy & 1) * 16;
    int bnf = blockIdx.z; int b = bnf >> 3, nf = bnf & 7;
    float acc[16];
    float bias = dwb[c];
    #pragma unroll
    for (int i = 0; i < 16; ++i) acc[i] = bias;
    const float* basep = h1 + (size_t)b*LSEQ*HID + c;
    #pragma unroll
    for (int dn = 0; dn < 3; ++dn){
        int pn = nf + dn - 1;
        if (pn < 0 || pn >= NFR) continue;   // block-uniform
        float wt9[9];
        #pragma unroll
        for (int i = 0; i < 9; ++i) wt9[i] = dwwT[(size_t)(dn*9 + i)*HID + c];
        #pragma unroll
        for (int dh = 0; dh < 3; ++dh){
            int ph = h + dh - 1;
            if (ph < 0 || ph >= HH) continue; // block-uniform
            const float* row = basep + ((size_t)pn*1024 + (size_t)ph*32)*HID;
            float w_a = (w0 > 0) ? row[(size_t)(w0-1)*HID] : 0.f;
            float w_b = row[(size_t)w0*HID];
            float q0 = wt9[dh*3+0], q1 = wt9[dh*3+1], q2 = wt9[dh*3+2];
            #pragma unroll
            for (int xw = 0; xw < 16; ++xw){
                int wn = w0 + xw + 1;
                float w_c = (wn < WW) ? row[(size_t)wn*HID] : 0.f;
                acc[xw] += w_a*q0 + w_b*q1 + w_c*q2;
                w_a = w_b; w_b = w_c;
            }
        }
    }
    unsigned short* orow = h2 + ((size_t)b*LSEQ + nf*1024 + h*32 + w0)*HID + c;
    #pragma unroll
    for (int xw = 0; xw < 16; ++xw)
        orow[(size_t)xw*HID] = f2bf(geluf(acc[xw]));
}

// ================================================================
extern "C" void kernel_launch(void* const* d_in, const int* in_sizes, int n_in,
                              void* d_out, int out_size, void* d_ws, size_t ws_size,
                              hipStream_t stream)
{
    const float* x     = (const float*)d_in[0];
    const float* fx    = (const float*)d_in[1];
    const int*   hc    = (const int*)  d_in[2];
    const float* ln1w  = (const float*)d_in[3];
    const float* ln1b  = (const float*)d_in[4];
    const float* inpw  = (const float*)d_in[5];
    const float* convw = (const float*)d_in[6];
    const float* convb = (const float*)d_in[7];
    const float* xpw   = (const float*)d_in[8];
    const float* dtw   = (const float*)d_in[9];
    const float* dtb   = (const float*)d_in[10];
    const float* alog  = (const float*)d_in[11];
    const float* dp    = (const float*)d_in[12];
    const float* outpw = (const float*)d_in[13];
    const float* ssaw  = (const float*)d_in[14];
    const float* ln2w  = (const float*)d_in[15];
    const float* ln2b  = (const float*)d_in[16];
    const float* fc1w  = (const float*)d_in[17];
    const float* fc1b  = (const float*)d_in[18];
    const float* dww   = (const float*)d_in[19];
    const float* dwb   = (const float*)d_in[20];
    const float* fc2w  = (const float*)d_in[21];
    const float* fc2b  = (const float*)d_in[22];

    float* ws = (float*)d_ws;
    float* x_flat = ws + OFF_XFLAT;
    float* f_flat = ws + OFF_FFLAT;
    float* xz     = ws + OFF_XZ;
    float* xc_f   = ws + OFF_XCF;
    float* xc_r   = ws + OFF_XCR;
    float* dbl_f  = ws + OFF_DBLF;
    float* dbl_r  = ws + OFF_DBLR;
    float* dt_f   = ws + OFF_DTF;
    float* dt_r   = ws + OFF_DTR;
    float* m_f    = ws + OFF_MF;
    float* m_r    = ws + OFF_MR_;
    float* h1     = ws + OFF_H1;
    float* pkbuf  = ws + OFF_PK;
    float* xm     = ws + OFF_XM;
    float* part   = ws + OFF_PART;
    float* dwwT   = ws + OFF_PART;
    float* aw     = ws + OFF_AW;
    float* cA     = ws + OFF_CA;
    float* cB     = ws + OFF_CB;
    float* cH     = ws + OFF_CHS;
    float* outm   = ws + OFF_NORM;
    int*   inv    = (int*)(ws + OFF_INV);
    unsigned short* wbf    = (unsigned short*)(ws + OFF_WBF);
    unsigned short* inpw_b = wbf + WB_INP;
    unsigned short* outpw_b= wbf + WB_OUT;
    unsigned short* fc1w_b = wbf + WB_FC1;
    unsigned short* fc2w_b = wbf + WB_FC2;
    unsigned short* nrm_bf = (unsigned short*)(ws + OFF_NORM);
    unsigned short* gf_bf  = (unsigned short*)(ws + OFF_GF);
    unsigned short* gr_bf  = (unsigned short*)(ws + OFF_GR);
    unsigned short* h2_bf  = (unsigned short*)(ws + OFF_H2);
    float* outp   = (float*)d_out;

    // 0. inverse permutation + weight conversions
    k_inv<<<LSEQ/256, 256, 0, stream>>>(hc, inv);
    k_wcvt<<<(int)((WB_TOT + 255)/256), 256, 0, stream>>>(inpw, outpw, fc1w, fc2w, wbf);
    // 1. gather + LN1
    k_gather_ln<<<dim3(32, NFR, B_N*2), 256, 0, stream>>>(x, fx, inv, ln1w, ln1b, x_flat, f_flat, nrm_bf);
    // 2. in_proj
    k_bgemm<0><<<dim3(128,3), 256, 0, stream>>>(nrm_bf, inpw_b, nullptr, nullptr, xz, DIMD, DIMD, DIMD);
    // 3. causal/anti-causal depthwise conv + silu
    k_conv<<<dim3(LSEQ/64, B_N), 256, 0, stream>>>(xz, convw, convb, xc_f, xc_r);
    // 4. x-proj
    k_dbl<<<dim3(MR/64, 2), 256, 0, stream>>>(xc_f, xc_r, xpw, dbl_f, dbl_r);
    // 5. dt projection + softplus
    k_dt<<<dim3(MR/8, 2), 192, 0, stream>>>(dbl_f, dbl_r, dtw, dtb, dt_f, dt_r);
    // 6. chunked selective scans
    k_scan_p1<<<dim3(NCH, B_N, 2), 384, 0, stream>>>(dt_f, dt_r, dbl_f, dbl_r, xc_f, xc_r, alog, cA, cB);
    k_scan_p2<<<dim3(DI*16/256, B_N, 2), 256, 0, stream>>>(cA, cB, cH);
    k_scan_p3<<<dim3(NCH, B_N, 2), 384, 0, stream>>>(dt_f, dt_r, dbl_f, dbl_r, xc_f, xc_r, xz, alog, dp, cH, gf_bf, gr_bf);
    // 7. out_proj
    k_bgemm<0><<<dim3(128,3), 256, 0, stream>>>(gf_bf, outpw_b, nullptr, nullptr, m_f, DIMD, DI, DI);
    k_bgemm<0><<<dim3(128,3), 256, 0, stream>>>(gr_bf, outpw_b, nullptr, nullptr, m_r, DIMD, DI, DI);
    // 8. SSA
    k_pool<<<dim3(6,PSL), 384, 0, stream>>>(m_f, m_r, f_flat, part);
    k_ssa<<<B_N, 384, 0, stream>>>(part, ssaw, aw);
    k_wt<<<(27*HID + 255)/256, 256, 0, stream>>>(dww, dwwT);
    // 9. fused xm + LN2, then MLP
    k_xm_ln<<<MR, 128, 0, stream>>>(x_flat, m_f, m_r, f_flat, aw, ln2w, ln2b, xm, nrm_bf);
    k_bgemm<1><<<dim3(128,12), 256, 0, stream>>>(nrm_bf, fc1w_b, fc1b, nullptr, h1, HID, DIMD, DIMD);
    k_dwconv<<<dim3(6,64,16), 256, 0, stream>>>(h1, dwwT, dwb, h2_bf);
    // 10. fc2 split-K=4
    k_bgemm_sk<<<dim3(128,3,4), 256, 0, stream>>>(h2_bf, fc2w_b, fc2b, xm, outm, pkbuf, DIMD, HID/4, HID);
    // 11. transpose-scatter
    k_scatter<<<dim3(32, NFR, B_N), 256, 0, stream>>>(outm, pkbuf, inv, outp);
}